// Round 17
// baseline (871.477 us; speedup 1.0000x reference)
//
#include <hip/hip_runtime.h>

#define HG 256
#define WGD 256
#define NN (HG*WGD)
#define NL 6

typedef _Float16 f16;
typedef _Float16 f16x8 __attribute__((ext_vector_type(8)));
typedef float f32x4 __attribute__((ext_vector_type(4)));

__device__ __forceinline__ void gload_lds16(const f16* g, f16* lds) {
  __builtin_amdgcn_global_load_lds(
      (const __attribute__((address_space(1))) unsigned int*)g,
      (__attribute__((address_space(3))) unsigned int*)lds, 16, 0, 0);
}

// ---- repack weights into fragment-major layout ----
__global__ __launch_bounds__(256) void repack_frag(
    const f16* __restrict__ BtU, const f16* __restrict__ BtPQ,
    f16* __restrict__ BUf, f16* __restrict__ BPQf)
{
  int l = blockIdx.y, zz = blockIdx.z;
  int t = blockIdx.x*256 + threadIdx.x;   // 16384 per (l,zz)
  int f = t >> 6;
  int lane = t & 63;
  if (zz == 0) {
    int NSs = (l==0) ? 8 : 16;
    if (f >= 16*NSs) return;
    int w2fn = f / NSs, ktks = f % NSs;
    int row = w2fn*16 + (lane & 15);
    int col = ktks*32 + (lane >> 4)*8;
    const f16* src = BtU + (size_t)l*131072 + ((l==0)?256:0) + (size_t)row*512 + col;
    *(f16x8*)(BUf + (size_t)l*131072 + (size_t)f*512 + lane*8) = *(const f16x8*)src;
  } else {
    if (l == 0) return;
    int ktks = f & 7, hw = f >> 3;
    int row = hw*16 + (lane & 15);
    int col = ktks*32 + (lane >> 4)*8;
    const f16* src = BtPQ + (size_t)l*131072 + (size_t)row*256 + col;
    *(f16x8*)(BPQf + (size_t)l*131072 + (size_t)f*512 + lane*8) = *(const f16x8*)src;
  }
}

// ---- FULLY-FUSED layer kernel: R gather + U-gemm + next-PQ-gemm ----
// R (this block's 64x256 tile) computed into REGISTERS up-front from PQin
// (or analytically from g for layer 1), then ds_written into the swizzled As
// tile at kt 4..7 (all kt for L1) — R never touches HBM; edge_fuse deleted.
// Phase 1: U[64x256] = relu([U|R]@BtU^T + epi), in-place on Ust (blocks only
//   touch their own rows). A LDS-dbuf; bf prefetched 1 kt ahead (R16).
// Phase 2 (DOPQ): PQout[64x512] = U_lds @ BtPQ^T + pqb; barrier-free.
// EPI: 1 +bias+deg*v2, relu | 3 EPI1 + g*avec (layer-1, no A operand)
template<int KK, int EPI, int DOPQ>
__global__ __launch_bounds__(512,4) void gemm_merge(
    const f16* __restrict__ A, int lda,        // U state (null for L1)
    const f16* __restrict__ PQin,              // [N][512] (null for L1)
    const f16* __restrict__ BUf_,              // fragment-major, NSs = KK/32
    const f16* __restrict__ BPQf_,             // fragment-major
    f16* __restrict__ Uo,                      // [N][256]
    f16* __restrict__ PQo,                     // [N][512]
    const float* __restrict__ bias,
    const float* __restrict__ v2,
    const float* __restrict__ avec,
    const int* __restrict__ gridv,
    const float* __restrict__ bias2,
    const float* __restrict__ cvecL,
    const float* __restrict__ wsiL,
    const float* __restrict__ wsjL,
    const float* __restrict__ pa,
    const float* __restrict__ pc)
{
  constexpr int NT = KK/64;
  constexpr int NSs = KK/32;
  __shared__ f16 sh[16384];   // 32 KB: As dbuf [0,4096)+[4096,8192); UL [0,16384)
  const int tid  = threadIdx.x;
  const int lane = tid & 63;
  const int w    = tid >> 6;          // 0..7 (N-wave)

  int bid = blockIdx.x;
  bid = (bid & 7) * 128 + (bid >> 3);   // band swizzle (1024 blocks)
  const int mbase = bid * 64;

  f32x4 acc[4][2];
#pragma unroll
  for (int a=0;a<4;a++)
#pragma unroll
    for (int b=0;b<2;b++) acc[a][b] = (f32x4){0.f,0.f,0.f,0.f};

  const int r8  = lane >> 3;
  const int c8s = ((lane & 7) ^ r8) * 8;
  const f16* BUlane  = BUf_  + lane*8;
  const f16* BPQlane = (DOPQ ? BPQf_ : BUf_) + lane*8;

  // ---- R gather: row rT = tid>>3, cols cb..cb+32 ----
  const int rT = tid >> 3;
  const int cb = (tid & 7) * 32;
  const int DIa[4] = {-1,1,0,0};
  const int DJa[4] = {0,0,-1,1};
  f16x8 rr[4];
  {
    const int n  = mbase + rT;
    const int gi = n >> 8, gj = n & 255;
    float gq = 0.f;
    if (EPI==3) gq = (float)gridv[n];
#pragma unroll
    for (int e=0;e<4;++e){
      const int ce = cb + e*8;
      float q[8], a8[8];
      if (EPI==3) {
#pragma unroll
        for (int k2=0;k2<8;k2++) q[k2] = gq*pa[256+ce+k2] + pc[256+ce+k2];
      } else {
        f16x8 qv = *(const f16x8*)&PQin[(size_t)n*512 + 256 + ce];
#pragma unroll
        for (int k2=0;k2<8;k2++) q[k2] = (float)qv[k2];
      }
#pragma unroll
      for (int k2=0;k2<8;k2++) a8[k2]=0.f;
#pragma unroll
      for (int d=0; d<4; ++d) {
        int si = gi - DIa[d], sj = gj - DJa[d];
        if (si>=0 && si<HG && sj>=0 && sj<WGD) {
          int sn = si*WGD + sj;
          float fsi = si*(1.f/HG), fsj = sj*(1.f/WGD);
          float pvf[8];
          if (EPI==3) {
            float gs = (float)gridv[sn];
#pragma unroll
            for (int k2=0;k2<8;k2++) pvf[k2] = gs*pa[ce+k2] + pc[ce+k2];
          } else {
            f16x8 pv = *(const f16x8*)&PQin[(size_t)sn*512 + ce];
#pragma unroll
            for (int k2=0;k2<8;k2++) pvf[k2] = (float)pv[k2];
          }
#pragma unroll
          for (int k2=0;k2<8;k2++) {
            float v = pvf[k2] + q[k2] + cvecL[d*256+ce+k2]
                    + fsi*wsiL[ce+k2] + fsj*wsjL[ce+k2];
            a8[k2] += fmaxf(v, 0.f);
          }
        }
      }
      f16x8 o;
#pragma unroll
      for (int k2=0;k2<8;k2++) o[k2] = (f16)a8[k2];
      rr[e] = o;
    }
  }

#define ASB(b) (sh + (b)*4096)
#define UL (sh)

  // stage chunk kt_: U via gload_lds (kt<4, non-L1) else R via ds_write
#define STAGEC(kt_, buf_)                                                      \
  { if (EPI!=3 && (kt_) < 4) {                                                 \
      gload_lds16(A + (size_t)(mbase + w*8 + r8)*lda + (kt_)*64 + c8s,         \
                  ASB(buf_) + w*512);                                          \
    } else {                                                                   \
      const int cch = (EPI==3) ? (kt_) : (kt_)-4;                              \
      if (((tid & 7) >> 1) == cch) {                                           \
        const int halfc = tid & 1;                                             \
        _Pragma("unroll")                                                      \
        for (int e=0;e<4;++e) {                                                \
          int pb = (halfc*4 + e) ^ (rT & 7);                                   \
          *(f16x8*)(ASB(buf_) + rT*64 + pb*8) = rr[e];                         \
        }                                                                      \
      }                                                                        \
    }                                                                          \
  }

  // prime: bf for kt=0 + chunk 0
  f16x8 bfc[2][2];
#pragma unroll
  for (int ks=0; ks<2; ++ks)
#pragma unroll
    for (int fn=0; fn<2; ++fn)
      bfc[ks][fn] = *(const f16x8*)(BUlane + (size_t)((w*2+fn)*NSs + ks)*512);
  STAGEC(0, 0);
  __syncthreads();
  int cur = 0;
  for (int kt = 0; kt < NT; ++kt) {
    if (kt + 1 < NT) STAGEC(kt + 1, cur ^ 1);
    f16x8 bfn[2][2];
    if (kt + 1 < NT) {
#pragma unroll
      for (int ks=0; ks<2; ++ks)
#pragma unroll
        for (int fn=0; fn<2; ++fn)
          bfn[ks][fn] = *(const f16x8*)(BUlane +
                          (size_t)((w*2+fn)*NSs + (kt+1)*2+ks)*512);
    }
    const f16* Acur = ASB(cur);
#pragma unroll
    for (int ks=0; ks<2; ++ks) {
      const int off = (((ks*4 + (lane>>4)) ^ (lane & 7)) * 8);
      f16x8 af[4];
#pragma unroll
      for (int fm=0; fm<4; ++fm)
        af[fm] = *(const f16x8*)&Acur[(fm*16 + (lane&15))*64 + off];
#pragma unroll
      for (int fm=0; fm<4; ++fm)
#pragma unroll
        for (int fn=0; fn<2; ++fn)
          acc[fm][fn] = __builtin_amdgcn_mfma_f32_16x16x32_f16(af[fm], bfc[ks][fn], acc[fm][fn], 0,0,0);
    }
    __syncthreads();
#pragma unroll
    for (int ks=0; ks<2; ++ks)
#pragma unroll
      for (int fn=0; fn<2; ++fn)
        bfc[ks][fn] = bfn[ks][fn];
    cur ^= 1;
  }
#undef STAGEC

  // ---- phase-1 epilogue: U -> global (in-place rows) AND swizzled LDS ----
#pragma unroll
  for (int fm=0; fm<4; ++fm) {
#pragma unroll
    for (int fn=0; fn<2; ++fn) {
      const int coll = w*32 + fn*16 + (lane&15);
#pragma unroll
      for (int r=0;r<4;r++) {
        int rl  = fm*16 + (lane>>4)*4 + r;
        int row = mbase + rl;
        float v = acc[fm][fn][r];
        int i = row >> 8, j = row & 255;
        float deg = (float)((i>0)+(i<255)+(j>0)+(j<255));
        v += bias[coll] + deg * v2[coll];
        if (EPI==3) v += (float)gridv[row] * avec[coll];
        v = fmaxf(v, 0.f);
        f16 hv = (f16)v;
        Uo[(size_t)row*256 + coll] = hv;
        if (DOPQ) {
          int sblk = (coll >> 3) ^ (rl & 7);
          UL[rl*256 + sblk*8 + (coll & 7)] = hv;
        }
      }
    }
  }

  if (DOPQ) {
    __syncthreads();   // UL visible; barrier-free from here on
#pragma unroll
    for (int h=0; h<2; ++h) {
      f32x4 acc2[4][2];
#pragma unroll
      for (int a=0;a<4;a++)
#pragma unroll
        for (int b=0;b<2;b++) acc2[a][b] = (f32x4){0.f,0.f,0.f,0.f};
#pragma unroll
      for (int kt=0; kt<4; ++kt) {
#pragma unroll
        for (int ks=0; ks<2; ++ks) {
          f16x8 af[4], bf[2];
#pragma unroll
          for (int fn=0; fn<2; ++fn)
            bf[fn] = *(const f16x8*)(BPQlane +
                       (size_t)(((h*16 + w*2+fn)*8) + kt*2+ks)*512);
#pragma unroll
          for (int fm=0; fm<4; ++fm) {
            int rl = fm*16 + (lane&15);
            int sblk = (kt*8 + ks*4 + (lane>>4)) ^ (rl & 7);
            af[fm] = *(const f16x8*)&UL[rl*256 + sblk*8];
          }
#pragma unroll
          for (int fm=0; fm<4; ++fm)
#pragma unroll
            for (int fn=0; fn<2; ++fn)
              acc2[fm][fn] = __builtin_amdgcn_mfma_f32_16x16x32_f16(af[fm], bf[fn], acc2[fm][fn], 0,0,0);
        }
      }
      const float* b2 = bias2 + h*256;
#pragma unroll
      for (int fm=0; fm<4; ++fm) {
#pragma unroll
        for (int fn=0; fn<2; ++fn) {
          const int coll = w*32 + fn*16 + (lane&15);
#pragma unroll
          for (int r=0;r<4;r++) {
            int row = mbase + fm*16 + (lane>>4)*4 + r;
            PQo[(size_t)row*512 + h*256 + coll] = (f16)(acc2[fm][fn][r] + b2[coll]);
          }
        }
      }
    }
  }
#undef UL
#undef ASB
}

// ---- 4-wave 128x128 GEMM core (K=256), used by the merged fold dispatch ----
__device__ __forceinline__ void gemm_core256(
    const f16* __restrict__ A, int lda,
    const f16* __restrict__ Bt, int ldb,
    f16* __restrict__ C, int ldc,
    int mbase, int nbase, f16* As, f16* Bs)
{
  const int tid  = threadIdx.x;
  const int lane = tid & 63;
  const int w    = tid >> 6;
  const int wm   = w >> 1, wn = w & 1;

  f32x4 acc[4][4];
#pragma unroll
  for (int a=0;a<4;a++)
#pragma unroll
    for (int b=0;b<4;b++) acc[a][b] = (f32x4){0.f,0.f,0.f,0.f};

  const int r8  = lane >> 3;
  const int c8s = ((lane & 7) ^ r8) * 8;

  for (int kt = 0; kt < 4; ++kt) {
    const f16* Ab = A  + (size_t)(mbase + w*32)*lda + kt*64;
    const f16* Bb = Bt + (size_t)(nbase + w*32)*ldb + kt*64;
#pragma unroll
    for (int i=0;i<4;i++) {
      gload_lds16(Ab + (size_t)(i*8 + r8)*lda + c8s, &As[(w*32+i*8)*64]);
      gload_lds16(Bb + (size_t)(i*8 + r8)*ldb + c8s, &Bs[(w*32+i*8)*64]);
    }
    __syncthreads();
#pragma unroll
    for (int ks=0; ks<2; ++ks) {
      const int off = (((ks*4 + (lane>>4)) ^ (lane & 7)) * 8);
      f16x8 af[4], bf[4];
#pragma unroll
      for (int fm=0; fm<4; ++fm)
        af[fm] = *(const f16x8*)&As[(wm*64 + fm*16 + (lane&15))*64 + off];
#pragma unroll
      for (int fn=0; fn<4; ++fn)
        bf[fn] = *(const f16x8*)&Bs[(wn*64 + fn*16 + (lane&15))*64 + off];
#pragma unroll
      for (int fm=0; fm<4; ++fm)
#pragma unroll
        for (int fn=0; fn<4; ++fn)
          acc[fm][fn] = __builtin_amdgcn_mfma_f32_16x16x32_f16(af[fm], bf[fn], acc[fm][fn], 0,0,0);
    }
    __syncthreads();
  }

  const int row0 = mbase + wm*64 + (lane>>4)*4;
  const int col0 = nbase + wn*64 + (lane&15);
#pragma unroll
  for (int fm=0; fm<4; ++fm)
#pragma unroll
    for (int fn=0; fn<4; ++fn)
#pragma unroll
      for (int r=0;r<4;r++)
        C[(size_t)(row0 + fm*16 + r)*ldc + (col0 + fn*16)] = (f16)acc[fm][fn][r];
}

// all 4 weight-fold GEMMs in one dispatch (86 blocks)
__global__ __launch_bounds__(256) void fold_all(
    const f16* __restrict__ BtA,  const f16* __restrict__ uW2h,
    const f16* __restrict__ mW2h, const f16* __restrict__ uW1aT,
    const f16* __restrict__ uW1bT,const f16* __restrict__ oWTh,
    f16* __restrict__ BtPQ, f16* __restrict__ BtU, f16* __restrict__ Wp2t)
{
  __shared__ f16 As[128*64];
  __shared__ f16 Bs[128*64];
  const int b = blockIdx.x;
  if (b < 40) {
    int z = b >> 3, rem = b & 7, x = rem & 3, y = rem >> 2;
    gemm_core256(BtA + (size_t)(z+1)*131072, 256, uW2h + (size_t)z*65536, 256,
                 BtPQ + (size_t)(z+1)*131072, 256, x*128, y*128, As, Bs);
  } else if (b < 60) {
    int rem = b - 40, z = rem >> 2, r2 = rem & 3, x = r2 & 1, y = r2 >> 1;
    gemm_core256(uW1aT + (size_t)(z+1)*65536, 256, uW2h + (size_t)z*65536, 256,
                 BtU + (size_t)(z+1)*131072, 512, x*128, y*128, As, Bs);
  } else if (b < 84) {
    int rem = b - 60, z = rem >> 2, r2 = rem & 3, x = r2 & 1, y = r2 >> 1;
    gemm_core256(uW1bT + (size_t)z*65536, 256, mW2h + (size_t)z*65536, 256,
                 BtU + (size_t)z*131072 + 256, 512, x*128, y*128, As, Bs);
  } else {
    int y = b - 84;
    gemm_core256(oWTh, 256, uW2h + (size_t)5*65536, 256,
                 Wp2t, 256, 0, y*128, As, Bs);
  }
}

// out[n,0..9] = U6[n,:] @ Wp2t^T + ob2  via MFMA, 1 wave = 16 nodes
__global__ __launch_bounds__(256) void out_mfma(
    const f16* __restrict__ U,        // [N][256]
    const f16* __restrict__ Wp2t,     // [128][256], rows >=10 zero
    const float* __restrict__ ob2,
    float* __restrict__ out)
{
  int lane = threadIdx.x & 63;
  int wv   = threadIdx.x >> 6;
  int nbase = blockIdx.x*64 + wv*16;
  f32x4 acc = (f32x4){0.f,0.f,0.f,0.f};
  int r  = lane & 15;
  int kg = (lane >> 4) * 8;
  const f16* Up = U + (size_t)(nbase + r)*256 + kg;
  const f16* Bp = Wp2t + r*256 + kg;
#pragma unroll
  for (int kt=0; kt<8; ++kt) {
    f16x8 af = *(const f16x8*)(Up + kt*32);
    f16x8 bf = *(const f16x8*)(Bp + kt*32);
    acc = __builtin_amdgcn_mfma_f32_16x16x32_f16(af, bf, acc, 0,0,0);
  }
  int col = lane & 15;
  int row0 = (lane>>4)*4;
  if (col < 10) {
    float bo = ob2[col];
#pragma unroll
    for (int rr=0; rr<4; ++rr)
      out[(size_t)(nbase + row0 + rr)*10 + col] = acc[rr] + bo;
  }
}

// ---- prep: everything small + all transpose-casts in ONE dispatch ----
__global__ __launch_bounds__(256) void prep_small(
    const float* __restrict__ uW2, const float* __restrict__ mW2,
    const float* __restrict__ oW,  const float* __restrict__ mW1,
    const float* __restrict__ mb1, const float* __restrict__ mb2,
    const float* __restrict__ uW1, const float* __restrict__ ub1,
    const float* __restrict__ ub2, const float* __restrict__ nb,
    const float* __restrict__ nW,  const float* __restrict__ ob,
    f16* __restrict__ uW2h, f16* __restrict__ mW2h, f16* __restrict__ oWTh,
    float* __restrict__ cvec, float* __restrict__ wsi_, float* __restrict__ wsj_,
    float* __restrict__ v2, float* __restrict__ ubias, float* __restrict__ avec,
    float* __restrict__ pqb, float* __restrict__ pa, float* __restrict__ pc,
    float* __restrict__ ob2,
    f16* __restrict__ BtA, f16* __restrict__ uW1aT, f16* __restrict__ uW1bT)
{
  __shared__ float red[3][4][64];
  __shared__ float tbuf[32][33];
  const int b = blockIdx.x;
  const int tid = threadIdx.x;
  if (b < 1536) {
    int idx = b*256 + tid;
    uW2h[idx] = (f16)uW2[idx];
    mW2h[idx] = (f16)mW2[idx];
  } else if (b < 1664) {
    int c = b - 1536, j = tid;
    oWTh[c*256 + j] = (c < 10) ? (f16)oW[j*10 + c] : (f16)0.f;
  } else if (b < 1670) {
    int l = b - 1664, j = tid;
    const float* base = mW1 + (size_t)l*516*256;
    float w512 = base[512*256 + j], w513 = base[513*256 + j];
    float b1 = mb1[l*256 + j];
    const int DI[4] = {-1,1,0,0};
    const int DJ[4] = {0,0,-1,1};
    for (int d=0;d<4;d++)
      cvec[(l*4+d)*256 + j] = (float)DI[d]*w512 + (float)DJ[d]*w513 + b1;
    wsi_[l*256+j] = base[514*256 + j];
    wsj_[l*256+j] = base[515*256 + j];
  } else if (b < 1694) {
    int pr = tid & 63, q = tid >> 6;
    int pair = (b-1670)*64 + pr;
    int l = pair >> 8, j = pair & 255;
    const float* prevb = l ? (ub2 + (l-1)*256) : nb;
    float s1=0.f, s2=0.f, s3=0.f;
    for (int t = q*64; t < q*64+64; ++t) {
      s1 += mb2[l*256+t] * uW1[((size_t)l*512+256+t)*256 + j];
      s2 += prevb[t]     * uW1[((size_t)l*512+t)*256 + j];
      if (l==0) s3 += nW[t] * uW1[(size_t)t*256 + j];
    }
    red[0][q][pr]=s1; red[1][q][pr]=s2; red[2][q][pr]=s3;
    __syncthreads();
    if (q==0) {
      float a = red[0][0][pr]+red[0][1][pr]+red[0][2][pr]+red[0][3][pr];
      float bb = red[1][0][pr]+red[1][1][pr]+red[1][2][pr]+red[1][3][pr];
      v2[pair] = a;
      ubias[pair] = ub1[pair] + bb;
      if (l==0) avec[j] = red[2][0][pr]+red[2][1][pr]+red[2][2][pr]+red[2][3][pr];
    }
  } else if (b < 1742) {
    int pr = tid & 63, q = tid >> 6;
    int pair = (b-1694)*64 + pr;
    int l = pair >> 9, c = pair & 511;
    int rowoff = (c < 256) ? 0 : 256;
    int cc = c & 255;
    const float* base = mW1 + (size_t)l*516*256 + (size_t)rowoff*256 + cc;
    float s1=0.f, s2=0.f;
    if (l==0) {
      for (int j=q*64; j<q*64+64; ++j) { float wv = base[(size_t)j*256]; s1 += nW[j]*wv; s2 += nb[j]*wv; }
    } else {
      const float* pb = ub2 + (l-1)*256;
      for (int j=q*64; j<q*64+64; ++j) s1 += pb[j]*base[(size_t)j*256];
    }
    red[0][q][pr]=s1; red[1][q][pr]=s2;
    __syncthreads();
    if (q==0) {
      float a = red[0][0][pr]+red[0][1][pr]+red[0][2][pr]+red[0][3][pr];
      if (l==0) { pa[c]=a; pc[c]=red[1][0][pr]+red[1][1][pr]+red[1][2][pr]+red[1][3][pr]; }
      else pqb[pair] = a;
    }
  } else if (b == 1742) {
    int c = tid >> 4, jg = tid & 15;
    float s = 0.f;
    if (c < 10)
      for (int j=jg*16; j<jg*16+16; ++j) s += ub2[5*256+j]*oW[j*10+c];
    red[0][c>>2][(c&3)*16+jg] = s;
    __syncthreads();
    if (jg==0 && c < 16) {
      float a=0.f;
      for (int t2=0;t2<16;t2++) a += red[0][c>>2][(c&3)*16+t2];
      ob2[c] = (c < 10) ? a + ob[c] : 0.f;
    }
  } else {
    int t = b - 1743;
    int z = t >> 6, rem = t & 63;
    int bxs = (rem & 7) * 32, bys = (rem >> 3) * 32;
    const int q = z / 6, l = z % 6;
    const float* s;
    f16* d;
    if (q == 0)      { s = mW1 + (size_t)l*516*256;          d = BtA   + (size_t)l*131072; }
    else if (q == 1) { s = mW1 + (size_t)l*516*256 + 65536;  d = BtA   + (size_t)l*131072 + 65536; }
    else if (q == 2) { s = uW1 + (size_t)l*131072;           d = uW1aT + (size_t)l*65536; }
    else             { s = uW1 + (size_t)l*131072 + 65536;   d = uW1bT + (size_t)l*65536; }
    const int tx = tid & 31, ty = tid >> 5;
#pragma unroll
    for (int rr=0; rr<4; ++rr)
      tbuf[ty+rr*8][tx] = s[(size_t)(bys+ty+rr*8)*256 + bxs+tx];
    __syncthreads();
#pragma unroll
    for (int rr=0; rr<4; ++rr)
      d[(size_t)(bxs+ty+rr*8)*256 + bys+tx] = (f16)tbuf[tx][ty+rr*8];
  }
}

extern "C" void kernel_launch(void* const* d_in, const int* in_sizes, int n_in,
                              void* d_out, int out_size, void* d_ws, size_t ws_size,
                              hipStream_t stream)
{
  const int*   gridv = (const int*) d_in[0];
  const float* nW   = (const float*)d_in[3];
  const float* nb   = (const float*)d_in[4];
  const float* mW1  = (const float*)d_in[5];
  const float* mb1  = (const float*)d_in[6];
  const float* mW2  = (const float*)d_in[7];
  const float* mb2  = (const float*)d_in[8];
  const float* uW1  = (const float*)d_in[9];
  const float* ub1  = (const float*)d_in[10];
  const float* uW2  = (const float*)d_in[11];
  const float* ub2  = (const float*)d_in[12];
  const float* oW   = (const float*)d_in[13];
  const float* ob   = (const float*)d_in[14];
  float* out = (float*)d_out;

  char* ws = (char*)d_ws;
  size_t off = 0;
  f16* Ust  = (f16*)(ws + off); off += (size_t)NN*256*2;   // 32MB, in-place
  f16* PQa  = (f16*)(ws + off); off += (size_t)NN*512*2;
  f16* PQb  = (f16*)(ws + off); off += (size_t)NN*512*2;
  f16* BtA  = (f16*)(ws + off); off += 6*512*256*2;
  f16* BtPQ = (f16*)(ws + off); off += 6*512*256*2;   // slot 0 unused
  f16* BtU  = (f16*)(ws + off); off += 6*256*512*2;
  f16* BUf  = (f16*)(ws + off); off += 6*131072*2;    // fragment-major BtU
  f16* BPQf = (f16*)(ws + off); off += 6*131072*2;    // fragment-major BtPQ
  f16* uW2h = (f16*)(ws + off); off += 6*256*256*2;
  f16* mW2h = (f16*)(ws + off); off += 6*256*256*2;
  f16* uW1aT= (f16*)(ws + off); off += 6*256*256*2;
  f16* uW1bT= (f16*)(ws + off); off += 6*256*256*2;
  f16* oWTh = (f16*)(ws + off); off += 128*256*2;
  f16* Wp2t = (f16*)(ws + off); off += 128*256*2;
  float* cvec = (float*)(ws + off); off += 6*4*256*4;
  float* wsi_ = (float*)(ws + off); off += 6*256*4;
  float* wsj_ = (float*)(ws + off); off += 6*256*4;
  float* v2   = (float*)(ws + off); off += 6*256*4;
  float* ubias= (float*)(ws + off); off += 6*256*4;
  float* pqb  = (float*)(ws + off); off += 6*512*4;   // slot 0 unused
  float* pa   = (float*)(ws + off); off += 512*4;
  float* pc   = (float*)(ws + off); off += 512*4;
  float* avec = (float*)(ws + off); off += 256*4;
  float* ob2  = (float*)(ws + off); off += 16*4;

  // ---- prep (3 dispatches) ----
  prep_small<<<3279,256,0,stream>>>(uW2, mW2, oW, mW1, mb1, mb2, uW1, ub1, ub2,
                                    nb, nW, ob,
                                    uW2h, mW2h, oWTh, cvec, wsi_, wsj_,
                                    v2, ubias, avec, pqb, pa, pc, ob2,
                                    BtA, uW1aT, uW1bT);
  fold_all<<<86,256,0,stream>>>(BtA, uW2h, mW2h, uW1aT, uW1bT, oWTh,
                                BtPQ, BtU, Wp2t);
  repack_frag<<<dim3(64,6,2),256,0,stream>>>(BtU, BtPQ, BUf, BPQf);

  // ---- layer 1: fused R(analytic) + U_1 + PQ_2 ----
  gemm_merge<256,3,1><<<1024,512,0,stream>>>(
      nullptr, 256, nullptr, BUf, BPQf + (size_t)1*131072,
      Ust, PQa, ubias, v2, avec, gridv, pqb + 1*512,
      cvec, wsi_, wsj_, pa, pc);

  // ---- layers 2..5: fused R(PQ) + U_l + PQ_{l+1} ----
  f16* pin = PQa; f16* pout = PQb;
  for (int l=1;l<5;l++){
    gemm_merge<512,1,1><<<1024,512,0,stream>>>(
        Ust, 256, pin, BUf + (size_t)l*131072, BPQf + (size_t)(l+1)*131072,
        Ust, pout, ubias + l*256, v2 + l*256, nullptr, nullptr,
        pqb + (l+1)*512, cvec + l*1024, wsi_ + l*256, wsj_ + l*256,
        nullptr, nullptr);
    f16* t = pin; pin = pout; pout = t;
  }

  // ---- layer 6: fused R(PQ) + U_6 (no PQ phase) ----
  gemm_merge<512,1,0><<<1024,512,0,stream>>>(
      Ust, 256, pin, BUf + (size_t)5*131072, nullptr,
      Ust, nullptr, ubias + 5*256, v2 + 5*256, nullptr, nullptr,
      nullptr, cvec + 5*1024, wsi_ + 5*256, wsj_ + 5*256,
      nullptr, nullptr);

  // out = U6 @ Wp2t^T + ob2
  out_mfma<<<1024,256,0,stream>>>(Ust, Wp2t, ob2, out);
}

// Round 18
// 433.136 us; speedup vs baseline: 2.0120x; 2.0120x over previous
//
#include <hip/hip_runtime.h>

#define HG 256
#define WGD 256
#define NN (HG*WGD)
#define NL 6

typedef _Float16 f16;
typedef _Float16 f16x8 __attribute__((ext_vector_type(8)));
typedef float f32x4 __attribute__((ext_vector_type(4)));

__device__ __forceinline__ void gload_lds16(const f16* g, f16* lds) {
  __builtin_amdgcn_global_load_lds(
      (const __attribute__((address_space(1))) unsigned int*)g,
      (__attribute__((address_space(3))) unsigned int*)lds, 16, 0, 0);
}

// ---- repack weights into fragment-major layout ----
__global__ __launch_bounds__(256) void repack_frag(
    const f16* __restrict__ BtU, const f16* __restrict__ BtPQ,
    f16* __restrict__ BUf, f16* __restrict__ BPQf)
{
  int l = blockIdx.y, zz = blockIdx.z;
  int t = blockIdx.x*256 + threadIdx.x;   // 16384 per (l,zz)
  int f = t >> 6;
  int lane = t & 63;
  if (zz == 0) {
    int NSs = (l==0) ? 8 : 16;
    if (f >= 16*NSs) return;
    int w2fn = f / NSs, ktks = f % NSs;
    int row = w2fn*16 + (lane & 15);
    int col = ktks*32 + (lane >> 4)*8;
    const f16* src = BtU + (size_t)l*131072 + ((l==0)?256:0) + (size_t)row*512 + col;
    *(f16x8*)(BUf + (size_t)l*131072 + (size_t)f*512 + lane*8) = *(const f16x8*)src;
  } else {
    if (l == 0) return;
    int ktks = f & 7, hw = f >> 3;
    int row = hw*16 + (lane & 15);
    int col = ktks*32 + (lane >> 4)*8;
    const f16* src = BtPQ + (size_t)l*131072 + (size_t)row*256 + col;
    *(f16x8*)(BPQf + (size_t)l*131072 + (size_t)f*512 + lane*8) = *(const f16x8*)src;
  }
}

// ---- MERGED layer kernel, BM=64, 32KB LDS (R14 structure) + bf PREFETCH ----
// Phase 1: U_l[64x256] = relu([U|R]@BtU^T + epi). A LDS-dbuf (2x8KB, 1
//   barrier/kt); B fragments prefetched ONE KT AHEAD into registers
//   (bfc/bfn double-buffer) so their L2 latency hides under the current kt's
//   MFMA + barrier (compiler can't hoist global loads across the fence).
// Phase 2 (DOPQ): PQ[64x512] = U_lds @ BtPQ^T + pqb. UL 32KB overlays As;
//   barrier-free.
// EPI: 1 +bias+deg*v2, relu | 3 EPI1 + g*avec (layer-1)
template<int KK, int EPI, int DOPQ>
__global__ __launch_bounds__(512,4) void gemm_merge(
    const f16* __restrict__ A, int lda,
    const f16* __restrict__ BUf_,   // fragment-major, NSs = KK/32
    const f16* __restrict__ BPQf_,  // fragment-major
    f16* __restrict__ Uo,           // ldc 512, cols 0..255
    f16* __restrict__ PQo,          // [N][512]
    const float* __restrict__ bias,
    const float* __restrict__ v2,
    const float* __restrict__ avec,
    const int* __restrict__ gridv,
    const float* __restrict__ bias2)
{
  constexpr int NT = KK/64;
  constexpr int NSs = KK/32;
  __shared__ f16 sh[16384];   // 32 KB: As dbuf [0,4096)+[4096,8192); UL [0,16384)
  const int tid  = threadIdx.x;
  const int lane = tid & 63;
  const int w    = tid >> 6;          // 0..7 (N-wave)

  int bid = blockIdx.x;
  bid = (bid & 7) * 128 + (bid >> 3);   // band swizzle (1024 blocks)
  const int mbase = bid * 64;

  f32x4 acc[4][2];
#pragma unroll
  for (int a=0;a<4;a++)
#pragma unroll
    for (int b=0;b<2;b++) acc[a][b] = (f32x4){0.f,0.f,0.f,0.f};

  const int r8  = lane >> 3;                 // 0..7
  const int c8s = ((lane & 7) ^ r8) * 8;     // A-stage pre-swizzled src col
  const f16* BUlane  = BUf_  + lane*8;
  const f16* BPQlane = (DOPQ ? BPQf_ : BUf_) + lane*8;

#define ASB(b) (sh + (b)*4096)
#define UL (sh)

#define STAGEA(kt, buf)                                                        \
  gload_lds16(A + (size_t)(mbase + w*8 + r8)*lda + (kt)*64 + c8s,              \
              ASB(buf) + w*512);

  // prime: bf for kt=0 + A tile 0
  f16x8 bfc[2][2];
#pragma unroll
  for (int ks=0; ks<2; ++ks)
#pragma unroll
    for (int fn=0; fn<2; ++fn)
      bfc[ks][fn] = *(const f16x8*)(BUlane + (size_t)((w*2+fn)*NSs + ks)*512);
  STAGEA(0, 0);
  __syncthreads();
  int cur = 0;
  for (int kt = 0; kt < NT; ++kt) {
    if (kt + 1 < NT) STAGEA(kt + 1, cur ^ 1);
    // prefetch next kt's B fragments BEFORE this kt's barrier
    f16x8 bfn[2][2];
    if (kt + 1 < NT) {
#pragma unroll
      for (int ks=0; ks<2; ++ks)
#pragma unroll
        for (int fn=0; fn<2; ++fn)
          bfn[ks][fn] = *(const f16x8*)(BUlane +
                          (size_t)((w*2+fn)*NSs + (kt+1)*2+ks)*512);
    }
    const f16* Acur = ASB(cur);
#pragma unroll
    for (int ks=0; ks<2; ++ks) {
      const int off = (((ks*4 + (lane>>4)) ^ (lane & 7)) * 8);
      f16x8 af[4];
#pragma unroll
      for (int fm=0; fm<4; ++fm)
        af[fm] = *(const f16x8*)&Acur[(fm*16 + (lane&15))*64 + off];
#pragma unroll
      for (int fm=0; fm<4; ++fm)
#pragma unroll
        for (int fn=0; fn<2; ++fn)
          acc[fm][fn] = __builtin_amdgcn_mfma_f32_16x16x32_f16(af[fm], bfc[ks][fn], acc[fm][fn], 0,0,0);
    }
    __syncthreads();
#pragma unroll
    for (int ks=0; ks<2; ++ks)
#pragma unroll
      for (int fn=0; fn<2; ++fn)
        bfc[ks][fn] = bfn[ks][fn];
    cur ^= 1;
  }
#undef STAGEA

  // ---- phase-1 epilogue: U -> global AND swizzled LDS (UL) ----
#pragma unroll
  for (int fm=0; fm<4; ++fm) {
#pragma unroll
    for (int fn=0; fn<2; ++fn) {
      const int coll = w*32 + fn*16 + (lane&15);
#pragma unroll
      for (int r=0;r<4;r++) {
        int rl  = fm*16 + (lane>>4)*4 + r;
        int row = mbase + rl;
        float v = acc[fm][fn][r];
        int i = row >> 8, j = row & 255;
        float deg = (float)((i>0)+(i<255)+(j>0)+(j<255));
        v += bias[coll] + deg * v2[coll];
        if (EPI==3) v += (float)gridv[row] * avec[coll];
        v = fmaxf(v, 0.f);
        f16 hv = (f16)v;
        Uo[(size_t)row*512 + coll] = hv;
        if (DOPQ) {
          int sblk = (coll >> 3) ^ (rl & 7);
          UL[rl*256 + sblk*8 + (coll & 7)] = hv;
        }
      }
    }
  }

  if (DOPQ) {
    __syncthreads();   // UL visible; barrier-free from here on
#pragma unroll
    for (int h=0; h<2; ++h) {
      f32x4 acc2[4][2];
#pragma unroll
      for (int a=0;a<4;a++)
#pragma unroll
        for (int b=0;b<2;b++) acc2[a][b] = (f32x4){0.f,0.f,0.f,0.f};
#pragma unroll
      for (int kt=0; kt<4; ++kt) {
#pragma unroll
        for (int ks=0; ks<2; ++ks) {
          f16x8 af[4], bf[2];
#pragma unroll
          for (int fn=0; fn<2; ++fn)
            bf[fn] = *(const f16x8*)(BPQlane +
                       (size_t)(((h*16 + w*2+fn)*8) + kt*2+ks)*512);
#pragma unroll
          for (int fm=0; fm<4; ++fm) {
            int rl = fm*16 + (lane&15);
            int sblk = (kt*8 + ks*4 + (lane>>4)) ^ (rl & 7);
            af[fm] = *(const f16x8*)&UL[rl*256 + sblk*8];
          }
#pragma unroll
          for (int fm=0; fm<4; ++fm)
#pragma unroll
            for (int fn=0; fn<2; ++fn)
              acc2[fm][fn] = __builtin_amdgcn_mfma_f32_16x16x32_f16(af[fm], bf[fn], acc2[fm][fn], 0,0,0);
        }
      }
      const float* b2 = bias2 + h*256;
#pragma unroll
      for (int fm=0; fm<4; ++fm) {
#pragma unroll
        for (int fn=0; fn<2; ++fn) {
          const int coll = w*32 + fn*16 + (lane&15);
#pragma unroll
          for (int r=0;r<4;r++) {
            int row = mbase + fm*16 + (lane>>4)*4 + r;
            PQo[(size_t)row*512 + h*256 + coll] = (f16)(acc2[fm][fn][r] + b2[coll]);
          }
        }
      }
    }
  }
#undef UL
}

// ---- 4-wave 128x128 GEMM core (K=256), used by the merged fold dispatch ----
__device__ __forceinline__ void gemm_core256(
    const f16* __restrict__ A, int lda,
    const f16* __restrict__ Bt, int ldb,
    f16* __restrict__ C, int ldc,
    int mbase, int nbase, f16* As, f16* Bs)
{
  const int tid  = threadIdx.x;
  const int lane = tid & 63;
  const int w    = tid >> 6;
  const int wm   = w >> 1, wn = w & 1;

  f32x4 acc[4][4];
#pragma unroll
  for (int a=0;a<4;a++)
#pragma unroll
    for (int b=0;b<4;b++) acc[a][b] = (f32x4){0.f,0.f,0.f,0.f};

  const int r8  = lane >> 3;
  const int c8s = ((lane & 7) ^ r8) * 8;

  for (int kt = 0; kt < 4; ++kt) {
    const f16* Ab = A  + (size_t)(mbase + w*32)*lda + kt*64;
    const f16* Bb = Bt + (size_t)(nbase + w*32)*ldb + kt*64;
#pragma unroll
    for (int i=0;i<4;i++) {
      gload_lds16(Ab + (size_t)(i*8 + r8)*lda + c8s, &As[(w*32+i*8)*64]);
      gload_lds16(Bb + (size_t)(i*8 + r8)*ldb + c8s, &Bs[(w*32+i*8)*64]);
    }
    __syncthreads();
#pragma unroll
    for (int ks=0; ks<2; ++ks) {
      const int off = (((ks*4 + (lane>>4)) ^ (lane & 7)) * 8);
      f16x8 af[4], bf[4];
#pragma unroll
      for (int fm=0; fm<4; ++fm)
        af[fm] = *(const f16x8*)&As[(wm*64 + fm*16 + (lane&15))*64 + off];
#pragma unroll
      for (int fn=0; fn<4; ++fn)
        bf[fn] = *(const f16x8*)&Bs[(wn*64 + fn*16 + (lane&15))*64 + off];
#pragma unroll
      for (int fm=0; fm<4; ++fm)
#pragma unroll
        for (int fn=0; fn<4; ++fn)
          acc[fm][fn] = __builtin_amdgcn_mfma_f32_16x16x32_f16(af[fm], bf[fn], acc[fm][fn], 0,0,0);
    }
    __syncthreads();
  }

  const int row0 = mbase + wm*64 + (lane>>4)*4;
  const int col0 = nbase + wn*64 + (lane&15);
#pragma unroll
  for (int fm=0; fm<4; ++fm)
#pragma unroll
    for (int fn=0; fn<4; ++fn)
#pragma unroll
      for (int r=0;r<4;r++)
        C[(size_t)(row0 + fm*16 + r)*ldc + (col0 + fn*16)] = (f16)acc[fm][fn][r];
}

// all 4 weight-fold GEMMs in one dispatch (86 blocks)
__global__ __launch_bounds__(256) void fold_all(
    const f16* __restrict__ BtA,  const f16* __restrict__ uW2h,
    const f16* __restrict__ mW2h, const f16* __restrict__ uW1aT,
    const f16* __restrict__ uW1bT,const f16* __restrict__ oWTh,
    f16* __restrict__ BtPQ, f16* __restrict__ BtU, f16* __restrict__ Wp2t)
{
  __shared__ f16 As[128*64];
  __shared__ f16 Bs[128*64];
  const int b = blockIdx.x;
  if (b < 40) {
    int z = b >> 3, rem = b & 7, x = rem & 3, y = rem >> 2;
    gemm_core256(BtA + (size_t)(z+1)*131072, 256, uW2h + (size_t)z*65536, 256,
                 BtPQ + (size_t)(z+1)*131072, 256, x*128, y*128, As, Bs);
  } else if (b < 60) {
    int rem = b - 40, z = rem >> 2, r2 = rem & 3, x = r2 & 1, y = r2 >> 1;
    gemm_core256(uW1aT + (size_t)(z+1)*65536, 256, uW2h + (size_t)z*65536, 256,
                 BtU + (size_t)(z+1)*131072, 512, x*128, y*128, As, Bs);
  } else if (b < 84) {
    int rem = b - 60, z = rem >> 2, r2 = rem & 3, x = r2 & 1, y = r2 >> 1;
    gemm_core256(uW1bT + (size_t)z*65536, 256, mW2h + (size_t)z*65536, 256,
                 BtU + (size_t)z*131072 + 256, 512, x*128, y*128, As, Bs);
  } else {
    int y = b - 84;
    gemm_core256(oWTh, 256, uW2h + (size_t)5*65536, 256,
                 Wp2t, 256, 0, y*128, As, Bs);
  }
}

// R[n] = sum over valid dirs of relu(P[src]+Q[n]+cvec_d+(si/256)*wsi+(sj/256)*wsj)
template<int R1>
__global__ __launch_bounds__(256) void edge_fuse(
    const f16* __restrict__ PQ, f16* __restrict__ UR,
    const float* __restrict__ cvec, const float* __restrict__ wsi_,
    const float* __restrict__ wsj_,
    const int* __restrict__ gridv, const float* __restrict__ pa,
    const float* __restrict__ pc)
{
  const int t  = threadIdx.x;
  const int ln = t >> 5, ch = t & 31;
  int bid = blockIdx.x;
  bid = (bid & 7) * 1024 + (bid >> 3);
  const int n  = bid*8 + ln;
  const int i  = n >> 8, j = n & 255;
  const int co = ch*8;

  float q[8], pa0[8], pc0[8];
  if (R1) {
    float g = (float)gridv[n];
#pragma unroll
    for (int e=0;e<8;e++) {
      pa0[e] = pa[co+e]; pc0[e] = pc[co+e];
      q[e] = g*pa[256+co+e] + pc[256+co+e];
    }
  } else {
    f16x8 qv = *(const f16x8*)&PQ[(size_t)n*512 + 256 + co];
#pragma unroll
    for (int e=0;e<8;e++) q[e] = (float)qv[e];
  }
  float wi[8], wj[8];
#pragma unroll
  for (int e=0;e<8;e++){ wi[e]=wsi_[co+e]; wj[e]=wsj_[co+e]; }
  float acc[8];
#pragma unroll
  for (int e=0;e<8;e++) acc[e]=0.f;

  const int DI[4] = {-1,1,0,0};
  const int DJ[4] = {0,0,-1,1};
#pragma unroll
  for (int d=0; d<4; ++d) {
    int si = i - DI[d], sj = j - DJ[d];
    if (si>=0 && si<HG && sj>=0 && sj<WGD) {
      int s = si*WGD + sj;
      float fsi = si * (1.f/HG), fsj = sj * (1.f/WGD);
      float pvf[8];
      if (R1) {
        float gs = (float)gridv[s];
#pragma unroll
        for (int e=0;e<8;e++) pvf[e] = gs*pa0[e] + pc0[e];
      } else {
        f16x8 pv = *(const f16x8*)&PQ[(size_t)s*512 + co];
#pragma unroll
        for (int e=0;e<8;e++) pvf[e] = (float)pv[e];
      }
#pragma unroll
      for (int e=0;e<8;e++) {
        float v = pvf[e] + q[e] + cvec[d*256+co+e] + fsi*wi[e] + fsj*wj[e];
        acc[e] += fmaxf(v, 0.f);
      }
    }
  }
  f16x8 outv;
#pragma unroll
  for (int e=0;e<8;e++) outv[e] = (f16)acc[e];
  *(f16x8*)&UR[(size_t)n*512 + 256 + co] = outv;
}

// out[n,0..9] = U6[n,:] @ Wp2t^T + ob2  via MFMA, 1 wave = 16 nodes
__global__ __launch_bounds__(256) void out_mfma(
    const f16* __restrict__ U,        // lda 512
    const f16* __restrict__ Wp2t,     // [128][256], rows >=10 zero
    const float* __restrict__ ob2,
    float* __restrict__ out)
{
  int lane = threadIdx.x & 63;
  int wv   = threadIdx.x >> 6;
  int nbase = blockIdx.x*64 + wv*16;
  f32x4 acc = (f32x4){0.f,0.f,0.f,0.f};
  int r  = lane & 15;
  int kg = (lane >> 4) * 8;
  const f16* Up = U + (size_t)(nbase + r)*512 + kg;
  const f16* Bp = Wp2t + r*256 + kg;
#pragma unroll
  for (int kt=0; kt<8; ++kt) {
    f16x8 af = *(const f16x8*)(Up + kt*32);
    f16x8 bf = *(const f16x8*)(Bp + kt*32);
    acc = __builtin_amdgcn_mfma_f32_16x16x32_f16(af, bf, acc, 0,0,0);
  }
  int col = lane & 15;
  int row0 = (lane>>4)*4;
  if (col < 10) {
    float bo = ob2[col];
#pragma unroll
    for (int rr=0; rr<4; ++rr)
      out[(size_t)(nbase + row0 + rr)*10 + col] = acc[rr] + bo;
  }
}

// ---- prep: everything small + all transpose-casts in ONE dispatch ----
__global__ __launch_bounds__(256) void prep_small(
    const float* __restrict__ uW2, const float* __restrict__ mW2,
    const float* __restrict__ oW,  const float* __restrict__ mW1,
    const float* __restrict__ mb1, const float* __restrict__ mb2,
    const float* __restrict__ uW1, const float* __restrict__ ub1,
    const float* __restrict__ ub2, const float* __restrict__ nb,
    const float* __restrict__ nW,  const float* __restrict__ ob,
    f16* __restrict__ uW2h, f16* __restrict__ mW2h, f16* __restrict__ oWTh,
    float* __restrict__ cvec, float* __restrict__ wsi_, float* __restrict__ wsj_,
    float* __restrict__ v2, float* __restrict__ ubias, float* __restrict__ avec,
    float* __restrict__ pqb, float* __restrict__ pa, float* __restrict__ pc,
    float* __restrict__ ob2,
    f16* __restrict__ BtA, f16* __restrict__ uW1aT, f16* __restrict__ uW1bT)
{
  __shared__ float red[3][4][64];
  __shared__ float tbuf[32][33];
  const int b = blockIdx.x;
  const int tid = threadIdx.x;
  if (b < 1536) {
    int idx = b*256 + tid;
    uW2h[idx] = (f16)uW2[idx];
    mW2h[idx] = (f16)mW2[idx];
  } else if (b < 1664) {
    int c = b - 1536, j = tid;
    oWTh[c*256 + j] = (c < 10) ? (f16)oW[j*10 + c] : (f16)0.f;
  } else if (b < 1670) {
    int l = b - 1664, j = tid;
    const float* base = mW1 + (size_t)l*516*256;
    float w512 = base[512*256 + j], w513 = base[513*256 + j];
    float b1 = mb1[l*256 + j];
    const int DI[4] = {-1,1,0,0};
    const int DJ[4] = {0,0,-1,1};
    for (int d=0;d<4;d++)
      cvec[(l*4+d)*256 + j] = (float)DI[d]*w512 + (float)DJ[d]*w513 + b1;
    wsi_[l*256+j] = base[514*256 + j];
    wsj_[l*256+j] = base[515*256 + j];
  } else if (b < 1694) {
    int pr = tid & 63, q = tid >> 6;
    int pair = (b-1670)*64 + pr;
    int l = pair >> 8, j = pair & 255;
    const float* prevb = l ? (ub2 + (l-1)*256) : nb;
    float s1=0.f, s2=0.f, s3=0.f;
    for (int t = q*64; t < q*64+64; ++t) {
      s1 += mb2[l*256+t] * uW1[((size_t)l*512+256+t)*256 + j];
      s2 += prevb[t]     * uW1[((size_t)l*512+t)*256 + j];
      if (l==0) s3 += nW[t] * uW1[(size_t)t*256 + j];
    }
    red[0][q][pr]=s1; red[1][q][pr]=s2; red[2][q][pr]=s3;
    __syncthreads();
    if (q==0) {
      float a = red[0][0][pr]+red[0][1][pr]+red[0][2][pr]+red[0][3][pr];
      float bb = red[1][0][pr]+red[1][1][pr]+red[1][2][pr]+red[1][3][pr];
      v2[pair] = a;
      ubias[pair] = ub1[pair] + bb;
      if (l==0) avec[j] = red[2][0][pr]+red[2][1][pr]+red[2][2][pr]+red[2][3][pr];
    }
  } else if (b < 1742) {
    int pr = tid & 63, q = tid >> 6;
    int pair = (b-1694)*64 + pr;
    int l = pair >> 9, c = pair & 511;
    int rowoff = (c < 256) ? 0 : 256;
    int cc = c & 255;
    const float* base = mW1 + (size_t)l*516*256 + (size_t)rowoff*256 + cc;
    float s1=0.f, s2=0.f;
    if (l==0) {
      for (int j=q*64; j<q*64+64; ++j) { float wv = base[(size_t)j*256]; s1 += nW[j]*wv; s2 += nb[j]*wv; }
    } else {
      const float* pb = ub2 + (l-1)*256;
      for (int j=q*64; j<q*64+64; ++j) s1 += pb[j]*base[(size_t)j*256];
    }
    red[0][q][pr]=s1; red[1][q][pr]=s2;
    __syncthreads();
    if (q==0) {
      float a = red[0][0][pr]+red[0][1][pr]+red[0][2][pr]+red[0][3][pr];
      if (l==0) { pa[c]=a; pc[c]=red[1][0][pr]+red[1][1][pr]+red[1][2][pr]+red[1][3][pr]; }
      else pqb[pair] = a;
    }
  } else if (b == 1742) {
    int c = tid >> 4, jg = tid & 15;
    float s = 0.f;
    if (c < 10)
      for (int j=jg*16; j<jg*16+16; ++j) s += ub2[5*256+j]*oW[j*10+c];
    red[0][c>>2][(c&3)*16+jg] = s;
    __syncthreads();
    if (jg==0 && c < 16) {
      float a=0.f;
      for (int t2=0;t2<16;t2++) a += red[0][c>>2][(c&3)*16+t2];
      ob2[c] = (c < 10) ? a + ob[c] : 0.f;
    }
  } else {
    int t = b - 1743;
    int z = t >> 6, rem = t & 63;
    int bxs = (rem & 7) * 32, bys = (rem >> 3) * 32;
    const int q = z / 6, l = z % 6;
    const float* s;
    f16* d;
    if (q == 0)      { s = mW1 + (size_t)l*516*256;          d = BtA   + (size_t)l*131072; }
    else if (q == 1) { s = mW1 + (size_t)l*516*256 + 65536;  d = BtA   + (size_t)l*131072 + 65536; }
    else if (q == 2) { s = uW1 + (size_t)l*131072;           d = uW1aT + (size_t)l*65536; }
    else             { s = uW1 + (size_t)l*131072 + 65536;   d = uW1bT + (size_t)l*65536; }
    const int tx = tid & 31, ty = tid >> 5;
#pragma unroll
    for (int rr=0; rr<4; ++rr)
      tbuf[ty+rr*8][tx] = s[(size_t)(bys+ty+rr*8)*256 + bxs+tx];
    __syncthreads();
#pragma unroll
    for (int rr=0; rr<4; ++rr)
      d[(size_t)(bxs+ty+rr*8)*256 + bys+tx] = (f16)tbuf[tx][ty+rr*8];
  }
}

extern "C" void kernel_launch(void* const* d_in, const int* in_sizes, int n_in,
                              void* d_out, int out_size, void* d_ws, size_t ws_size,
                              hipStream_t stream)
{
  const int*   gridv = (const int*) d_in[0];
  const float* nW   = (const float*)d_in[3];
  const float* nb   = (const float*)d_in[4];
  const float* mW1  = (const float*)d_in[5];
  const float* mb1  = (const float*)d_in[6];
  const float* mW2  = (const float*)d_in[7];
  const float* mb2  = (const float*)d_in[8];
  const float* uW1  = (const float*)d_in[9];
  const float* ub1  = (const float*)d_in[10];
  const float* uW2  = (const float*)d_in[11];
  const float* ub2  = (const float*)d_in[12];
  const float* oW   = (const float*)d_in[13];
  const float* ob   = (const float*)d_in[14];
  float* out = (float*)d_out;

  char* ws = (char*)d_ws;
  size_t off = 0;
  f16* URa  = (f16*)(ws + off); off += (size_t)NN*512*2;
  f16* URb  = (f16*)(ws + off); off += (size_t)NN*512*2;
  f16* PQ   = (f16*)(ws + off); off += (size_t)NN*512*2;
  f16* BtA  = (f16*)(ws + off); off += 6*512*256*2;
  f16* BtPQ = (f16*)(ws + off); off += 6*512*256*2;   // slot 0 unused
  f16* BtU  = (f16*)(ws + off); off += 6*256*512*2;
  f16* BUf  = (f16*)(ws + off); off += 6*131072*2;    // fragment-major BtU
  f16* BPQf = (f16*)(ws + off); off += 6*131072*2;    // fragment-major BtPQ
  f16* uW2h = (f16*)(ws + off); off += 6*256*256*2;
  f16* mW2h = (f16*)(ws + off); off += 6*256*256*2;
  f16* uW1aT= (f16*)(ws + off); off += 6*256*256*2;
  f16* uW1bT= (f16*)(ws + off); off += 6*256*256*2;
  f16* oWTh = (f16*)(ws + off); off += 128*256*2;
  f16* Wp2t = (f16*)(ws + off); off += 128*256*2;
  float* cvec = (float*)(ws + off); off += 6*4*256*4;
  float* wsi_ = (float*)(ws + off); off += 6*256*4;
  float* wsj_ = (float*)(ws + off); off += 6*256*4;
  float* v2   = (float*)(ws + off); off += 6*256*4;
  float* ubias= (float*)(ws + off); off += 6*256*4;
  float* pqb  = (float*)(ws + off); off += 6*512*4;   // slot 0 unused
  float* pa   = (float*)(ws + off); off += 512*4;
  float* pc   = (float*)(ws + off); off += 512*4;
  float* avec = (float*)(ws + off); off += 256*4;
  float* ob2  = (float*)(ws + off); off += 16*4;

  // ---- prep (3 dispatches) ----
  prep_small<<<3279,256,0,stream>>>(uW2, mW2, oW, mW1, mb1, mb2, uW1, ub1, ub2,
                                    nb, nW, ob,
                                    uW2h, mW2h, oWTh, cvec, wsi_, wsj_,
                                    v2, ubias, avec, pqb, pa, pc, ob2,
                                    BtA, uW1aT, uW1bT);
  fold_all<<<86,256,0,stream>>>(BtA, uW2h, mW2h, uW1aT, uW1bT, oWTh,
                                BtPQ, BtU, Wp2t);
  repack_frag<<<dim3(64,6,2),256,0,stream>>>(BtU, BtPQ, BUf, BPQf);

  // ---- layer 1: R_1 analytic, then merged U_1 + PQ_2 ----
  edge_fuse<1><<<8192,256,0,stream>>>(nullptr, URa, cvec, wsi_, wsj_, gridv, pa, pc);
  gemm_merge<256,3,1><<<1024,512,0,stream>>>(
      URa + 256, 512, BUf, BPQf + (size_t)1*131072,
      URb, PQ, ubias, v2, avec, gridv, pqb + 1*512);

  // ---- layers 2..5: edge_fuse + merged(U_l + PQ_{l+1}) ----
  f16* cur = URb; f16* nxt = URa;
  for (int l=1;l<5;l++){
    edge_fuse<0><<<8192,256,0,stream>>>(PQ, cur, cvec + l*1024, wsi_ + l*256, wsj_ + l*256,
                                        nullptr, nullptr, nullptr);
    gemm_merge<512,1,1><<<1024,512,0,stream>>>(
        cur, 512, BUf + (size_t)l*131072, BPQf + (size_t)(l+1)*131072,
        nxt, PQ, ubias + l*256, v2 + l*256, nullptr, nullptr, pqb + (l+1)*512);
    f16* t = cur; cur = nxt; nxt = t;
  }

  // ---- layer 6: edge_fuse + merged update (no PQ phase) ----
  edge_fuse<0><<<8192,256,0,stream>>>(PQ, cur, cvec + 5*1024, wsi_ + 5*256, wsj_ + 5*256,
                                      nullptr, nullptr, nullptr);
  gemm_merge<512,1,0><<<1024,512,0,stream>>>(
      cur, 512, BUf + (size_t)5*131072, nullptr,
      nxt, nullptr, ubias + 5*256, v2 + 5*256, nullptr, nullptr, nullptr);

  // out = U6 @ Wp2t^T + ob2
  out_mfma<<<1024,256,0,stream>>>(nxt, Wp2t, ob2, out);
}

// Round 19
// 428.302 us; speedup vs baseline: 2.0347x; 1.0113x over previous
//
#include <hip/hip_runtime.h>

#define HG 256
#define WGD 256
#define NN (HG*WGD)
#define NL 6

typedef _Float16 f16;
typedef _Float16 f16x8 __attribute__((ext_vector_type(8)));
typedef float f32x4 __attribute__((ext_vector_type(4)));

__device__ __forceinline__ void gload_lds16(const f16* g, f16* lds) {
  __builtin_amdgcn_global_load_lds(
      (const __attribute__((address_space(1))) unsigned int*)g,
      (__attribute__((address_space(3))) unsigned int*)lds, 16, 0, 0);
}

// ---- repack weights into fragment-major layout ----
__global__ __launch_bounds__(256) void repack_frag(
    const f16* __restrict__ BtU, const f16* __restrict__ BtPQ,
    f16* __restrict__ BUf, f16* __restrict__ BPQf)
{
  int l = blockIdx.y, zz = blockIdx.z;
  int t = blockIdx.x*256 + threadIdx.x;   // 16384 per (l,zz)
  int f = t >> 6;
  int lane = t & 63;
  if (zz == 0) {
    int NSs = (l==0) ? 8 : 16;
    if (f >= 16*NSs) return;
    int w2fn = f / NSs, ktks = f % NSs;
    int row = w2fn*16 + (lane & 15);
    int col = ktks*32 + (lane >> 4)*8;
    const f16* src = BtU + (size_t)l*131072 + ((l==0)?256:0) + (size_t)row*512 + col;
    *(f16x8*)(BUf + (size_t)l*131072 + (size_t)f*512 + lane*8) = *(const f16x8*)src;
  } else {
    if (l == 0) return;
    int ktks = f & 7, hw = f >> 3;
    int row = hw*16 + (lane & 15);
    int col = ktks*32 + (lane >> 4)*8;
    const f16* src = BtPQ + (size_t)l*131072 + (size_t)row*256 + col;
    *(f16x8*)(BPQf + (size_t)l*131072 + (size_t)f*512 + lane*8) = *(const f16x8*)src;
  }
}

// ---- MERGED layer kernel, BM=64, 33KB LDS + bf PREFETCH ----
// Phase 1: U_l[64x256] = relu([U|R]@BtU^T + epi). A LDS-dbuf (2x8KB, 1
//   barrier/kt, XOR-swizzled staging); B fragments prefetched ONE KT AHEAD
//   into registers (bfc/bfn) so their L2 latency hides under MFMA+barrier.
// Phase 2 (DOPQ): PQ[64x512] = U_lds @ BtPQ^T + pqb; barrier-free.
// UL uses PADDED row stride 264 f16 (528B: 16B-aligned, bank base rotates
//   by 4/row) with LINEAR writes — kills the epilogue's structural 2^21
//   bank-conflict cycles that the XOR layout had (all rows bank-0-based).
// EPI: 1 +bias+deg*v2, relu | 3 EPI1 + g*avec (layer-1)
template<int KK, int EPI, int DOPQ>
__global__ __launch_bounds__(512,4) void gemm_merge(
    const f16* __restrict__ A, int lda,
    const f16* __restrict__ BUf_,   // fragment-major, NSs = KK/32
    const f16* __restrict__ BPQf_,  // fragment-major
    f16* __restrict__ Uo,           // ldc 512, cols 0..255
    f16* __restrict__ PQo,          // [N][512]
    const float* __restrict__ bias,
    const float* __restrict__ v2,
    const float* __restrict__ avec,
    const int* __restrict__ gridv,
    const float* __restrict__ bias2)
{
  constexpr int NT = KK/64;
  constexpr int NSs = KK/32;
  constexpr int ULS = 264;    // padded UL row stride (f16)
  __shared__ f16 sh[16896];   // 33 KB: As dbuf [0,8192); UL [0,16896) overlays
  const int tid  = threadIdx.x;
  const int lane = tid & 63;
  const int w    = tid >> 6;          // 0..7 (N-wave)

  int bid = blockIdx.x;
  bid = (bid & 7) * 128 + (bid >> 3);   // band swizzle (1024 blocks)
  const int mbase = bid * 64;

  f32x4 acc[4][2];
#pragma unroll
  for (int a=0;a<4;a++)
#pragma unroll
    for (int b=0;b<2;b++) acc[a][b] = (f32x4){0.f,0.f,0.f,0.f};

  const int r8  = lane >> 3;                 // 0..7
  const int c8s = ((lane & 7) ^ r8) * 8;     // A-stage pre-swizzled src col
  const f16* BUlane  = BUf_  + lane*8;
  const f16* BPQlane = (DOPQ ? BPQf_ : BUf_) + lane*8;

#define ASB(b) (sh + (b)*4096)
#define UL (sh)

#define STAGEA(kt, buf)                                                        \
  gload_lds16(A + (size_t)(mbase + w*8 + r8)*lda + (kt)*64 + c8s,              \
              ASB(buf) + w*512);

  // prime: bf for kt=0 + A tile 0
  f16x8 bfc[2][2];
#pragma unroll
  for (int ks=0; ks<2; ++ks)
#pragma unroll
    for (int fn=0; fn<2; ++fn)
      bfc[ks][fn] = *(const f16x8*)(BUlane + (size_t)((w*2+fn)*NSs + ks)*512);
  STAGEA(0, 0);
  __syncthreads();
  int cur = 0;
  for (int kt = 0; kt < NT; ++kt) {
    if (kt + 1 < NT) STAGEA(kt + 1, cur ^ 1);
    // prefetch next kt's B fragments BEFORE this kt's barrier
    f16x8 bfn[2][2];
    if (kt + 1 < NT) {
#pragma unroll
      for (int ks=0; ks<2; ++ks)
#pragma unroll
        for (int fn=0; fn<2; ++fn)
          bfn[ks][fn] = *(const f16x8*)(BUlane +
                          (size_t)((w*2+fn)*NSs + (kt+1)*2+ks)*512);
    }
    const f16* Acur = ASB(cur);
#pragma unroll
    for (int ks=0; ks<2; ++ks) {
      const int off = (((ks*4 + (lane>>4)) ^ (lane & 7)) * 8);
      f16x8 af[4];
#pragma unroll
      for (int fm=0; fm<4; ++fm)
        af[fm] = *(const f16x8*)&Acur[(fm*16 + (lane&15))*64 + off];
#pragma unroll
      for (int fm=0; fm<4; ++fm)
#pragma unroll
        for (int fn=0; fn<2; ++fn)
          acc[fm][fn] = __builtin_amdgcn_mfma_f32_16x16x32_f16(af[fm], bfc[ks][fn], acc[fm][fn], 0,0,0);
    }
    __syncthreads();
#pragma unroll
    for (int ks=0; ks<2; ++ks)
#pragma unroll
      for (int fn=0; fn<2; ++fn)
        bfc[ks][fn] = bfn[ks][fn];
    cur ^= 1;
  }
#undef STAGEA

  // ---- phase-1 epilogue: U -> global AND padded-linear LDS (UL) ----
#pragma unroll
  for (int fm=0; fm<4; ++fm) {
#pragma unroll
    for (int fn=0; fn<2; ++fn) {
      const int coll = w*32 + fn*16 + (lane&15);
#pragma unroll
      for (int r=0;r<4;r++) {
        int rl  = fm*16 + (lane>>4)*4 + r;
        int row = mbase + rl;
        float v = acc[fm][fn][r];
        int i = row >> 8, j = row & 255;
        float deg = (float)((i>0)+(i<255)+(j>0)+(j<255));
        v += bias[coll] + deg * v2[coll];
        if (EPI==3) v += (float)gridv[row] * avec[coll];
        v = fmaxf(v, 0.f);
        f16 hv = (f16)v;
        Uo[(size_t)row*512 + coll] = hv;
        if (DOPQ) UL[rl*ULS + coll] = hv;
      }
    }
  }

  if (DOPQ) {
    __syncthreads();   // UL visible; barrier-free from here on
#pragma unroll
    for (int h=0; h<2; ++h) {
      f32x4 acc2[4][2];
#pragma unroll
      for (int a=0;a<4;a++)
#pragma unroll
        for (int b=0;b<2;b++) acc2[a][b] = (f32x4){0.f,0.f,0.f,0.f};
#pragma unroll
      for (int kt=0; kt<4; ++kt) {
#pragma unroll
        for (int ks=0; ks<2; ++ks) {
          f16x8 af[4], bf[2];
#pragma unroll
          for (int fn=0; fn<2; ++fn)
            bf[fn] = *(const f16x8*)(BPQlane +
                       (size_t)(((h*16 + w*2+fn)*8) + kt*2+ks)*512);
#pragma unroll
          for (int fm=0; fm<4; ++fm) {
            int rl = fm*16 + (lane&15);
            af[fm] = *(const f16x8*)&UL[rl*ULS + kt*64 + ks*32 + (lane>>4)*8];
          }
#pragma unroll
          for (int fm=0; fm<4; ++fm)
#pragma unroll
            for (int fn=0; fn<2; ++fn)
              acc2[fm][fn] = __builtin_amdgcn_mfma_f32_16x16x32_f16(af[fm], bf[fn], acc2[fm][fn], 0,0,0);
        }
      }
      const float* b2 = bias2 + h*256;
#pragma unroll
      for (int fm=0; fm<4; ++fm) {
#pragma unroll
        for (int fn=0; fn<2; ++fn) {
          const int coll = w*32 + fn*16 + (lane&15);
#pragma unroll
          for (int r=0;r<4;r++) {
            int row = mbase + fm*16 + (lane>>4)*4 + r;
            PQo[(size_t)row*512 + h*256 + coll] = (f16)(acc2[fm][fn][r] + b2[coll]);
          }
        }
      }
    }
  }
#undef UL
#undef ASB
}

// ---- 4-wave 128x128 GEMM core (K=256), used by the merged fold dispatch ----
__device__ __forceinline__ void gemm_core256(
    const f16* __restrict__ A, int lda,
    const f16* __restrict__ Bt, int ldb,
    f16* __restrict__ C, int ldc,
    int mbase, int nbase, f16* As, f16* Bs)
{
  const int tid  = threadIdx.x;
  const int lane = tid & 63;
  const int w    = tid >> 6;
  const int wm   = w >> 1, wn = w & 1;

  f32x4 acc[4][4];
#pragma unroll
  for (int a=0;a<4;a++)
#pragma unroll
    for (int b=0;b<4;b++) acc[a][b] = (f32x4){0.f,0.f,0.f,0.f};

  const int r8  = lane >> 3;
  const int c8s = ((lane & 7) ^ r8) * 8;

  for (int kt = 0; kt < 4; ++kt) {
    const f16* Ab = A  + (size_t)(mbase + w*32)*lda + kt*64;
    const f16* Bb = Bt + (size_t)(nbase + w*32)*ldb + kt*64;
#pragma unroll
    for (int i=0;i<4;i++) {
      gload_lds16(Ab + (size_t)(i*8 + r8)*lda + c8s, &As[(w*32+i*8)*64]);
      gload_lds16(Bb + (size_t)(i*8 + r8)*ldb + c8s, &Bs[(w*32+i*8)*64]);
    }
    __syncthreads();
#pragma unroll
    for (int ks=0; ks<2; ++ks) {
      const int off = (((ks*4 + (lane>>4)) ^ (lane & 7)) * 8);
      f16x8 af[4], bf[4];
#pragma unroll
      for (int fm=0; fm<4; ++fm)
        af[fm] = *(const f16x8*)&As[(wm*64 + fm*16 + (lane&15))*64 + off];
#pragma unroll
      for (int fn=0; fn<4; ++fn)
        bf[fn] = *(const f16x8*)&Bs[(wn*64 + fn*16 + (lane&15))*64 + off];
#pragma unroll
      for (int fm=0; fm<4; ++fm)
#pragma unroll
        for (int fn=0; fn<4; ++fn)
          acc[fm][fn] = __builtin_amdgcn_mfma_f32_16x16x32_f16(af[fm], bf[fn], acc[fm][fn], 0,0,0);
    }
    __syncthreads();
  }

  const int row0 = mbase + wm*64 + (lane>>4)*4;
  const int col0 = nbase + wn*64 + (lane&15);
#pragma unroll
  for (int fm=0; fm<4; ++fm)
#pragma unroll
    for (int fn=0; fn<4; ++fn)
#pragma unroll
      for (int r=0;r<4;r++)
        C[(size_t)(row0 + fm*16 + r)*ldc + (col0 + fn*16)] = (f16)acc[fm][fn][r];
}

// all 4 weight-fold GEMMs in one dispatch (86 blocks)
__global__ __launch_bounds__(256) void fold_all(
    const f16* __restrict__ BtA,  const f16* __restrict__ uW2h,
    const f16* __restrict__ mW2h, const f16* __restrict__ uW1aT,
    const f16* __restrict__ uW1bT,const f16* __restrict__ oWTh,
    f16* __restrict__ BtPQ, f16* __restrict__ BtU, f16* __restrict__ Wp2t)
{
  __shared__ f16 As[128*64];
  __shared__ f16 Bs[128*64];
  const int b = blockIdx.x;
  if (b < 40) {
    int z = b >> 3, rem = b & 7, x = rem & 3, y = rem >> 2;
    gemm_core256(BtA + (size_t)(z+1)*131072, 256, uW2h + (size_t)z*65536, 256,
                 BtPQ + (size_t)(z+1)*131072, 256, x*128, y*128, As, Bs);
  } else if (b < 60) {
    int rem = b - 40, z = rem >> 2, r2 = rem & 3, x = r2 & 1, y = r2 >> 1;
    gemm_core256(uW1aT + (size_t)(z+1)*65536, 256, uW2h + (size_t)z*65536, 256,
                 BtU + (size_t)(z+1)*131072, 512, x*128, y*128, As, Bs);
  } else if (b < 84) {
    int rem = b - 60, z = rem >> 2, r2 = rem & 3, x = r2 & 1, y = r2 >> 1;
    gemm_core256(uW1bT + (size_t)z*65536, 256, mW2h + (size_t)z*65536, 256,
                 BtU + (size_t)z*131072 + 256, 512, x*128, y*128, As, Bs);
  } else {
    int y = b - 84;
    gemm_core256(oWTh, 256, uW2h + (size_t)5*65536, 256,
                 Wp2t, 256, 0, y*128, As, Bs);
  }
}

// R[n] = sum over valid dirs of relu(P[src]+Q[n]+cvec_d+(si/256)*wsi+(sj/256)*wsj)
template<int R1>
__global__ __launch_bounds__(256) void edge_fuse(
    const f16* __restrict__ PQ, f16* __restrict__ UR,
    const float* __restrict__ cvec, const float* __restrict__ wsi_,
    const float* __restrict__ wsj_,
    const int* __restrict__ gridv, const float* __restrict__ pa,
    const float* __restrict__ pc)
{
  const int t  = threadIdx.x;
  const int ln = t >> 5, ch = t & 31;
  int bid = blockIdx.x;
  bid = (bid & 7) * 1024 + (bid >> 3);
  const int n  = bid*8 + ln;
  const int i  = n >> 8, j = n & 255;
  const int co = ch*8;

  float q[8], pa0[8], pc0[8];
  if (R1) {
    float g = (float)gridv[n];
#pragma unroll
    for (int e=0;e<8;e++) {
      pa0[e] = pa[co+e]; pc0[e] = pc[co+e];
      q[e] = g*pa[256+co+e] + pc[256+co+e];
    }
  } else {
    f16x8 qv = *(const f16x8*)&PQ[(size_t)n*512 + 256 + co];
#pragma unroll
    for (int e=0;e<8;e++) q[e] = (float)qv[e];
  }
  float wi[8], wj[8];
#pragma unroll
  for (int e=0;e<8;e++){ wi[e]=wsi_[co+e]; wj[e]=wsj_[co+e]; }
  float acc[8];
#pragma unroll
  for (int e=0;e<8;e++) acc[e]=0.f;

  const int DI[4] = {-1,1,0,0};
  const int DJ[4] = {0,0,-1,1};
#pragma unroll
  for (int d=0; d<4; ++d) {
    int si = i - DI[d], sj = j - DJ[d];
    if (si>=0 && si<HG && sj>=0 && sj<WGD) {
      int s = si*WGD + sj;
      float fsi = si * (1.f/HG), fsj = sj * (1.f/WGD);
      float pvf[8];
      if (R1) {
        float gs = (float)gridv[s];
#pragma unroll
        for (int e=0;e<8;e++) pvf[e] = gs*pa0[e] + pc0[e];
      } else {
        f16x8 pv = *(const f16x8*)&PQ[(size_t)s*512 + co];
#pragma unroll
        for (int e=0;e<8;e++) pvf[e] = (float)pv[e];
      }
#pragma unroll
      for (int e=0;e<8;e++) {
        float v = pvf[e] + q[e] + cvec[d*256+co+e] + fsi*wi[e] + fsj*wj[e];
        acc[e] += fmaxf(v, 0.f);
      }
    }
  }
  f16x8 outv;
#pragma unroll
  for (int e=0;e<8;e++) outv[e] = (f16)acc[e];
  *(f16x8*)&UR[(size_t)n*512 + 256 + co] = outv;
}

// out[n,0..9] = U6[n,:] @ Wp2t^T + ob2  via MFMA, 1 wave = 16 nodes
__global__ __launch_bounds__(256) void out_mfma(
    const f16* __restrict__ U,        // lda 512
    const f16* __restrict__ Wp2t,     // [128][256], rows >=10 zero
    const float* __restrict__ ob2,
    float* __restrict__ out)
{
  int lane = threadIdx.x & 63;
  int wv   = threadIdx.x >> 6;
  int nbase = blockIdx.x*64 + wv*16;
  f32x4 acc = (f32x4){0.f,0.f,0.f,0.f};
  int r  = lane & 15;
  int kg = (lane >> 4) * 8;
  const f16* Up = U + (size_t)(nbase + r)*512 + kg;
  const f16* Bp = Wp2t + r*256 + kg;
#pragma unroll
  for (int kt=0; kt<8; ++kt) {
    f16x8 af = *(const f16x8*)(Up + kt*32);
    f16x8 bf = *(const f16x8*)(Bp + kt*32);
    acc = __builtin_amdgcn_mfma_f32_16x16x32_f16(af, bf, acc, 0,0,0);
  }
  int col = lane & 15;
  int row0 = (lane>>4)*4;
  if (col < 10) {
    float bo = ob2[col];
#pragma unroll
    for (int rr=0; rr<4; ++rr)
      out[(size_t)(nbase + row0 + rr)*10 + col] = acc[rr] + bo;
  }
}

// ---- prep: everything small + all transpose-casts in ONE dispatch ----
__global__ __launch_bounds__(256) void prep_small(
    const float* __restrict__ uW2, const float* __restrict__ mW2,
    const float* __restrict__ oW,  const float* __restrict__ mW1,
    const float* __restrict__ mb1, const float* __restrict__ mb2,
    const float* __restrict__ uW1, const float* __restrict__ ub1,
    const float* __restrict__ ub2, const float* __restrict__ nb,
    const float* __restrict__ nW,  const float* __restrict__ ob,
    f16* __restrict__ uW2h, f16* __restrict__ mW2h, f16* __restrict__ oWTh,
    float* __restrict__ cvec, float* __restrict__ wsi_, float* __restrict__ wsj_,
    float* __restrict__ v2, float* __restrict__ ubias, float* __restrict__ avec,
    float* __restrict__ pqb, float* __restrict__ pa, float* __restrict__ pc,
    float* __restrict__ ob2,
    f16* __restrict__ BtA, f16* __restrict__ uW1aT, f16* __restrict__ uW1bT)
{
  __shared__ float red[3][4][64];
  __shared__ float tbuf[32][33];
  const int b = blockIdx.x;
  const int tid = threadIdx.x;
  if (b < 1536) {
    int idx = b*256 + tid;
    uW2h[idx] = (f16)uW2[idx];
    mW2h[idx] = (f16)mW2[idx];
  } else if (b < 1664) {
    int c = b - 1536, j = tid;
    oWTh[c*256 + j] = (c < 10) ? (f16)oW[j*10 + c] : (f16)0.f;
  } else if (b < 1670) {
    int l = b - 1664, j = tid;
    const float* base = mW1 + (size_t)l*516*256;
    float w512 = base[512*256 + j], w513 = base[513*256 + j];
    float b1 = mb1[l*256 + j];
    const int DI[4] = {-1,1,0,0};
    const int DJ[4] = {0,0,-1,1};
    for (int d=0;d<4;d++)
      cvec[(l*4+d)*256 + j] = (float)DI[d]*w512 + (float)DJ[d]*w513 + b1;
    wsi_[l*256+j] = base[514*256 + j];
    wsj_[l*256+j] = base[515*256 + j];
  } else if (b < 1694) {
    int pr = tid & 63, q = tid >> 6;
    int pair = (b-1670)*64 + pr;
    int l = pair >> 8, j = pair & 255;
    const float* prevb = l ? (ub2 + (l-1)*256) : nb;
    float s1=0.f, s2=0.f, s3=0.f;
    for (int t = q*64; t < q*64+64; ++t) {
      s1 += mb2[l*256+t] * uW1[((size_t)l*512+256+t)*256 + j];
      s2 += prevb[t]     * uW1[((size_t)l*512+t)*256 + j];
      if (l==0) s3 += nW[t] * uW1[(size_t)t*256 + j];
    }
    red[0][q][pr]=s1; red[1][q][pr]=s2; red[2][q][pr]=s3;
    __syncthreads();
    if (q==0) {
      float a = red[0][0][pr]+red[0][1][pr]+red[0][2][pr]+red[0][3][pr];
      float bb = red[1][0][pr]+red[1][1][pr]+red[1][2][pr]+red[1][3][pr];
      v2[pair] = a;
      ubias[pair] = ub1[pair] + bb;
      if (l==0) avec[j] = red[2][0][pr]+red[2][1][pr]+red[2][2][pr]+red[2][3][pr];
    }
  } else if (b < 1742) {
    int pr = tid & 63, q = tid >> 6;
    int pair = (b-1694)*64 + pr;
    int l = pair >> 9, c = pair & 511;
    int rowoff = (c < 256) ? 0 : 256;
    int cc = c & 255;
    const float* base = mW1 + (size_t)l*516*256 + (size_t)rowoff*256 + cc;
    float s1=0.f, s2=0.f;
    if (l==0) {
      for (int j=q*64; j<q*64+64; ++j) { float wv = base[(size_t)j*256]; s1 += nW[j]*wv; s2 += nb[j]*wv; }
    } else {
      const float* pb = ub2 + (l-1)*256;
      for (int j=q*64; j<q*64+64; ++j) s1 += pb[j]*base[(size_t)j*256];
    }
    red[0][q][pr]=s1; red[1][q][pr]=s2;
    __syncthreads();
    if (q==0) {
      float a = red[0][0][pr]+red[0][1][pr]+red[0][2][pr]+red[0][3][pr];
      if (l==0) { pa[c]=a; pc[c]=red[1][0][pr]+red[1][1][pr]+red[1][2][pr]+red[1][3][pr]; }
      else pqb[pair] = a;
    }
  } else if (b == 1742) {
    int c = tid >> 4, jg = tid & 15;
    float s = 0.f;
    if (c < 10)
      for (int j=jg*16; j<jg*16+16; ++j) s += ub2[5*256+j]*oW[j*10+c];
    red[0][c>>2][(c&3)*16+jg] = s;
    __syncthreads();
    if (jg==0 && c < 16) {
      float a=0.f;
      for (int t2=0;t2<16;t2++) a += red[0][c>>2][(c&3)*16+t2];
      ob2[c] = (c < 10) ? a + ob[c] : 0.f;
    }
  } else {
    int t = b - 1743;
    int z = t >> 6, rem = t & 63;
    int bxs = (rem & 7) * 32, bys = (rem >> 3) * 32;
    const int q = z / 6, l = z % 6;
    const float* s;
    f16* d;
    if (q == 0)      { s = mW1 + (size_t)l*516*256;          d = BtA   + (size_t)l*131072; }
    else if (q == 1) { s = mW1 + (size_t)l*516*256 + 65536;  d = BtA   + (size_t)l*131072 + 65536; }
    else if (q == 2) { s = uW1 + (size_t)l*131072;           d = uW1aT + (size_t)l*65536; }
    else             { s = uW1 + (size_t)l*131072 + 65536;   d = uW1bT + (size_t)l*65536; }
    const int tx = tid & 31, ty = tid >> 5;
#pragma unroll
    for (int rr=0; rr<4; ++rr)
      tbuf[ty+rr*8][tx] = s[(size_t)(bys+ty+rr*8)*256 + bxs+tx];
    __syncthreads();
#pragma unroll
    for (int rr=0; rr<4; ++rr)
      d[(size_t)(bxs+ty+rr*8)*256 + bys+tx] = (f16)tbuf[tx][ty+rr*8];
  }
}

extern "C" void kernel_launch(void* const* d_in, const int* in_sizes, int n_in,
                              void* d_out, int out_size, void* d_ws, size_t ws_size,
                              hipStream_t stream)
{
  const int*   gridv = (const int*) d_in[0];
  const float* nW   = (const float*)d_in[3];
  const float* nb   = (const float*)d_in[4];
  const float* mW1  = (const float*)d_in[5];
  const float* mb1  = (const float*)d_in[6];
  const float* mW2  = (const float*)d_in[7];
  const float* mb2  = (const float*)d_in[8];
  const float* uW1  = (const float*)d_in[9];
  const float* ub1  = (const float*)d_in[10];
  const float* uW2  = (const float*)d_in[11];
  const float* ub2  = (const float*)d_in[12];
  const float* oW   = (const float*)d_in[13];
  const float* ob   = (const float*)d_in[14];
  float* out = (float*)d_out;

  char* ws = (char*)d_ws;
  size_t off = 0;
  f16* URa  = (f16*)(ws + off); off += (size_t)NN*512*2;
  f16* URb  = (f16*)(ws + off); off += (size_t)NN*512*2;
  f16* PQ   = (f16*)(ws + off); off += (size_t)NN*512*2;
  f16* BtA  = (f16*)(ws + off); off += 6*512*256*2;
  f16* BtPQ = (f16*)(ws + off); off += 6*512*256*2;   // slot 0 unused
  f16* BtU  = (f16*)(ws + off); off += 6*256*512*2;
  f16* BUf  = (f16*)(ws + off); off += 6*131072*2;    // fragment-major BtU
  f16* BPQf = (f16*)(ws + off); off += 6*131072*2;    // fragment-major BtPQ
  f16* uW2h = (f16*)(ws + off); off += 6*256*256*2;
  f16* mW2h = (f16*)(ws + off); off += 6*256*256*2;
  f16* uW1aT= (f16*)(ws + off); off += 6*256*256*2;
  f16* uW1bT= (f16*)(ws + off); off += 6*256*256*2;
  f16* oWTh = (f16*)(ws + off); off += 128*256*2;
  f16* Wp2t = (f16*)(ws + off); off += 128*256*2;
  float* cvec = (float*)(ws + off); off += 6*4*256*4;
  float* wsi_ = (float*)(ws + off); off += 6*256*4;
  float* wsj_ = (float*)(ws + off); off += 6*256*4;
  float* v2   = (float*)(ws + off); off += 6*256*4;
  float* ubias= (float*)(ws + off); off += 6*256*4;
  float* pqb  = (float*)(ws + off); off += 6*512*4;   // slot 0 unused
  float* pa   = (float*)(ws + off); off += 512*4;
  float* pc   = (float*)(ws + off); off += 512*4;
  float* avec = (float*)(ws + off); off += 256*4;
  float* ob2  = (float*)(ws + off); off += 16*4;

  // ---- prep (3 dispatches) ----
  prep_small<<<3279,256,0,stream>>>(uW2, mW2, oW, mW1, mb1, mb2, uW1, ub1, ub2,
                                    nb, nW, ob,
                                    uW2h, mW2h, oWTh, cvec, wsi_, wsj_,
                                    v2, ubias, avec, pqb, pa, pc, ob2,
                                    BtA, uW1aT, uW1bT);
  fold_all<<<86,256,0,stream>>>(BtA, uW2h, mW2h, uW1aT, uW1bT, oWTh,
                                BtPQ, BtU, Wp2t);
  repack_frag<<<dim3(64,6,2),256,0,stream>>>(BtU, BtPQ, BUf, BPQf);

  // ---- layer 1: R_1 analytic, then merged U_1 + PQ_2 ----
  edge_fuse<1><<<8192,256,0,stream>>>(nullptr, URa, cvec, wsi_, wsj_, gridv, pa, pc);
  gemm_merge<256,3,1><<<1024,512,0,stream>>>(
      URa + 256, 512, BUf, BPQf + (size_t)1*131072,
      URb, PQ, ubias, v2, avec, gridv, pqb + 1*512);

  // ---- layers 2..5: edge_fuse + merged(U_l + PQ_{l+1}) ----
  f16* cur = URb; f16* nxt = URa;
  for (int l=1;l<5;l++){
    edge_fuse<0><<<8192,256,0,stream>>>(PQ, cur, cvec + l*1024, wsi_ + l*256, wsj_ + l*256,
                                        nullptr, nullptr, nullptr);
    gemm_merge<512,1,1><<<1024,512,0,stream>>>(
        cur, 512, BUf + (size_t)l*131072, BPQf + (size_t)(l+1)*131072,
        nxt, PQ, ubias + l*256, v2 + l*256, nullptr, nullptr, pqb + (l+1)*512);
    f16* t = cur; cur = nxt; nxt = t;
  }

  // ---- layer 6: edge_fuse + merged update (no PQ phase) ----
  edge_fuse<0><<<8192,256,0,stream>>>(PQ, cur, cvec + 5*1024, wsi_ + 5*256, wsj_ + 5*256,
                                      nullptr, nullptr, nullptr);
  gemm_merge<512,1,0><<<1024,512,0,stream>>>(
      cur, 512, BUf + (size_t)5*131072, nullptr,
      nxt, nullptr, ubias + 5*256, v2 + 5*256, nullptr, nullptr, nullptr);

  // out = U6 @ Wp2t^T + ob2
  out_mfma<<<1024,256,0,stream>>>(nxt, Wp2t, ob2, out);
}

// Round 21
// 428.106 us; speedup vs baseline: 2.0357x; 1.0005x over previous
//
#include <hip/hip_runtime.h>

#define HG 256
#define WGD 256
#define NN (HG*WGD)
#define NL 6

typedef _Float16 f16;
typedef _Float16 f16x8 __attribute__((ext_vector_type(8)));
typedef float f32x4 __attribute__((ext_vector_type(4)));

__device__ __forceinline__ void gload_lds16(const f16* g, f16* lds) {
  __builtin_amdgcn_global_load_lds(
      (const __attribute__((address_space(1))) unsigned int*)g,
      (__attribute__((address_space(3))) unsigned int*)lds, 16, 0, 0);
}

// ---- repack weights into fragment-major layout ----
__global__ __launch_bounds__(256) void repack_frag(
    const f16* __restrict__ BtU, const f16* __restrict__ BtPQ,
    f16* __restrict__ BUf, f16* __restrict__ BPQf)
{
  int l = blockIdx.y, zz = blockIdx.z;
  int t = blockIdx.x*256 + threadIdx.x;   // 16384 per (l,zz)
  int f = t >> 6;
  int lane = t & 63;
  if (zz == 0) {
    int NSs = (l==0) ? 8 : 16;
    if (f >= 16*NSs) return;
    int w2fn = f / NSs, ktks = f % NSs;
    int row = w2fn*16 + (lane & 15);
    int col = ktks*32 + (lane >> 4)*8;
    const f16* src = BtU + (size_t)l*131072 + ((l==0)?256:0) + (size_t)row*512 + col;
    *(f16x8*)(BUf + (size_t)l*131072 + (size_t)f*512 + lane*8) = *(const f16x8*)src;
  } else {
    if (l == 0) return;
    int ktks = f & 7, hw = f >> 3;
    int row = hw*16 + (lane & 15);
    int col = ktks*32 + (lane >> 4)*8;
    const f16* src = BtPQ + (size_t)l*131072 + (size_t)row*256 + col;
    *(f16x8*)(BPQf + (size_t)l*131072 + (size_t)f*512 + lane*8) = *(const f16x8*)src;
  }
}

// ---- MERGED layer kernel, BM=64, 33KB LDS + bf PREFETCH (R19 final) ----
// Phase 1: U_l[64x256] = relu([U|R]@BtU^T + epi). A LDS-dbuf (2x8KB, 1
//   barrier/kt, XOR-swizzled staging); B fragments prefetched ONE KT AHEAD
//   into registers (bfc/bfn) so their L2 latency hides under MFMA+barrier.
// Phase 2 (DOPQ): PQ[64x512] = U_lds @ BtPQ^T + pqb; barrier-free.
// UL uses PADDED row stride 264 f16 (528B: 16B-aligned, bank base rotates
//   by 4/row) with LINEAR writes.
// EPI: 1 +bias+deg*v2, relu | 3 EPI1 + g*avec (layer-1)
template<int KK, int EPI, int DOPQ>
__global__ __launch_bounds__(512,4) void gemm_merge(
    const f16* __restrict__ A, int lda,
    const f16* __restrict__ BUf_,   // fragment-major, NSs = KK/32
    const f16* __restrict__ BPQf_,  // fragment-major
    f16* __restrict__ Uo,           // ldc 512, cols 0..255
    f16* __restrict__ PQo,          // [N][512]
    const float* __restrict__ bias,
    const float* __restrict__ v2,
    const float* __restrict__ avec,
    const int* __restrict__ gridv,
    const float* __restrict__ bias2)
{
  constexpr int NT = KK/64;
  constexpr int NSs = KK/32;
  constexpr int ULS = 264;    // padded UL row stride (f16)
  __shared__ f16 sh[16896];   // 33 KB: As dbuf [0,8192); UL [0,16896) overlays
  const int tid  = threadIdx.x;
  const int lane = tid & 63;
  const int w    = tid >> 6;          // 0..7 (N-wave)

  int bid = blockIdx.x;
  bid = (bid & 7) * 128 + (bid >> 3);   // band swizzle (1024 blocks)
  const int mbase = bid * 64;

  f32x4 acc[4][2];
#pragma unroll
  for (int a=0;a<4;a++)
#pragma unroll
    for (int b=0;b<2;b++) acc[a][b] = (f32x4){0.f,0.f,0.f,0.f};

  const int r8  = lane >> 3;                 // 0..7
  const int c8s = ((lane & 7) ^ r8) * 8;     // A-stage pre-swizzled src col
  const f16* BUlane  = BUf_  + lane*8;
  const f16* BPQlane = (DOPQ ? BPQf_ : BUf_) + lane*8;

#define ASB(b) (sh + (b)*4096)
#define UL (sh)

#define STAGEA(kt, buf)                                                        \
  gload_lds16(A + (size_t)(mbase + w*8 + r8)*lda + (kt)*64 + c8s,              \
              ASB(buf) + w*512);

  // prime: bf for kt=0 + A tile 0
  f16x8 bfc[2][2];
#pragma unroll
  for (int ks=0; ks<2; ++ks)
#pragma unroll
    for (int fn=0; fn<2; ++fn)
      bfc[ks][fn] = *(const f16x8*)(BUlane + (size_t)((w*2+fn)*NSs + ks)*512);
  STAGEA(0, 0);
  __syncthreads();
  int cur = 0;
  for (int kt = 0; kt < NT; ++kt) {
    if (kt + 1 < NT) STAGEA(kt + 1, cur ^ 1);
    // prefetch next kt's B fragments BEFORE this kt's barrier
    f16x8 bfn[2][2];
    if (kt + 1 < NT) {
#pragma unroll
      for (int ks=0; ks<2; ++ks)
#pragma unroll
        for (int fn=0; fn<2; ++fn)
          bfn[ks][fn] = *(const f16x8*)(BUlane +
                          (size_t)((w*2+fn)*NSs + (kt+1)*2+ks)*512);
    }
    const f16* Acur = ASB(cur);
#pragma unroll
    for (int ks=0; ks<2; ++ks) {
      const int off = (((ks*4 + (lane>>4)) ^ (lane & 7)) * 8);
      f16x8 af[4];
#pragma unroll
      for (int fm=0; fm<4; ++fm)
        af[fm] = *(const f16x8*)&Acur[(fm*16 + (lane&15))*64 + off];
#pragma unroll
      for (int fm=0; fm<4; ++fm)
#pragma unroll
        for (int fn=0; fn<2; ++fn)
          acc[fm][fn] = __builtin_amdgcn_mfma_f32_16x16x32_f16(af[fm], bfc[ks][fn], acc[fm][fn], 0,0,0);
    }
    __syncthreads();
#pragma unroll
    for (int ks=0; ks<2; ++ks)
#pragma unroll
      for (int fn=0; fn<2; ++fn)
        bfc[ks][fn] = bfn[ks][fn];
    cur ^= 1;
  }
#undef STAGEA

  // ---- phase-1 epilogue: U -> global AND padded-linear LDS (UL) ----
#pragma unroll
  for (int fm=0; fm<4; ++fm) {
#pragma unroll
    for (int fn=0; fn<2; ++fn) {
      const int coll = w*32 + fn*16 + (lane&15);
#pragma unroll
      for (int r=0;r<4;r++) {
        int rl  = fm*16 + (lane>>4)*4 + r;
        int row = mbase + rl;
        float v = acc[fm][fn][r];
        int i = row >> 8, j = row & 255;
        float deg = (float)((i>0)+(i<255)+(j>0)+(j<255));
        v += bias[coll] + deg * v2[coll];
        if (EPI==3) v += (float)gridv[row] * avec[coll];
        v = fmaxf(v, 0.f);
        f16 hv = (f16)v;
        Uo[(size_t)row*512 + coll] = hv;
        if (DOPQ) UL[rl*ULS + coll] = hv;
      }
    }
  }

  if (DOPQ) {
    __syncthreads();   // UL visible; barrier-free from here on
#pragma unroll
    for (int h=0; h<2; ++h) {
      f32x4 acc2[4][2];
#pragma unroll
      for (int a=0;a<4;a++)
#pragma unroll
        for (int b=0;b<2;b++) acc2[a][b] = (f32x4){0.f,0.f,0.f,0.f};
#pragma unroll
      for (int kt=0; kt<4; ++kt) {
#pragma unroll
        for (int ks=0; ks<2; ++ks) {
          f16x8 af[4], bf[2];
#pragma unroll
          for (int fn=0; fn<2; ++fn)
            bf[fn] = *(const f16x8*)(BPQlane +
                       (size_t)(((h*16 + w*2+fn)*8) + kt*2+ks)*512);
#pragma unroll
          for (int fm=0; fm<4; ++fm) {
            int rl = fm*16 + (lane&15);
            af[fm] = *(const f16x8*)&UL[rl*ULS + kt*64 + ks*32 + (lane>>4)*8];
          }
#pragma unroll
          for (int fm=0; fm<4; ++fm)
#pragma unroll
            for (int fn=0; fn<2; ++fn)
              acc2[fm][fn] = __builtin_amdgcn_mfma_f32_16x16x32_f16(af[fm], bf[fn], acc2[fm][fn], 0,0,0);
        }
      }
      const float* b2 = bias2 + h*256;
#pragma unroll
      for (int fm=0; fm<4; ++fm) {
#pragma unroll
        for (int fn=0; fn<2; ++fn) {
          const int coll = w*32 + fn*16 + (lane&15);
#pragma unroll
          for (int r=0;r<4;r++) {
            int row = mbase + fm*16 + (lane>>4)*4 + r;
            PQo[(size_t)row*512 + h*256 + coll] = (f16)(acc2[fm][fn][r] + b2[coll]);
          }
        }
      }
    }
  }
#undef UL
#undef ASB
}

// ---- 4-wave 128x128 GEMM core (K=256), used by the merged fold dispatch ----
__device__ __forceinline__ void gemm_core256(
    const f16* __restrict__ A, int lda,
    const f16* __restrict__ Bt, int ldb,
    f16* __restrict__ C, int ldc,
    int mbase, int nbase, f16* As, f16* Bs)
{
  const int tid  = threadIdx.x;
  const int lane = tid & 63;
  const int w    = tid >> 6;
  const int wm   = w >> 1, wn = w & 1;

  f32x4 acc[4][4];
#pragma unroll
  for (int a=0;a<4;a++)
#pragma unroll
    for (int b=0;b<4;b++) acc[a][b] = (f32x4){0.f,0.f,0.f,0.f};

  const int r8  = lane >> 3;
  const int c8s = ((lane & 7) ^ r8) * 8;

  for (int kt = 0; kt < 4; ++kt) {
    const f16* Ab = A  + (size_t)(mbase + w*32)*lda + kt*64;
    const f16* Bb = Bt + (size_t)(nbase + w*32)*ldb + kt*64;
#pragma unroll
    for (int i=0;i<4;i++) {
      gload_lds16(Ab + (size_t)(i*8 + r8)*lda + c8s, &As[(w*32+i*8)*64]);
      gload_lds16(Bb + (size_t)(i*8 + r8)*ldb + c8s, &Bs[(w*32+i*8)*64]);
    }
    __syncthreads();
#pragma unroll
    for (int ks=0; ks<2; ++ks) {
      const int off = (((ks*4 + (lane>>4)) ^ (lane & 7)) * 8);
      f16x8 af[4], bf[4];
#pragma unroll
      for (int fm=0; fm<4; ++fm)
        af[fm] = *(const f16x8*)&As[(wm*64 + fm*16 + (lane&15))*64 + off];
#pragma unroll
      for (int fn=0; fn<4; ++fn)
        bf[fn] = *(const f16x8*)&Bs[(wn*64 + fn*16 + (lane&15))*64 + off];
#pragma unroll
      for (int fm=0; fm<4; ++fm)
#pragma unroll
        for (int fn=0; fn<4; ++fn)
          acc[fm][fn] = __builtin_amdgcn_mfma_f32_16x16x32_f16(af[fm], bf[fn], acc[fm][fn], 0,0,0);
    }
    __syncthreads();
  }

  const int row0 = mbase + wm*64 + (lane>>4)*4;
  const int col0 = nbase + wn*64 + (lane&15);
#pragma unroll
  for (int fm=0; fm<4; ++fm)
#pragma unroll
    for (int fn=0; fn<4; ++fn)
#pragma unroll
      for (int r=0;r<4;r++)
        C[(size_t)(row0 + fm*16 + r)*ldc + (col0 + fn*16)] = (f16)acc[fm][fn][r];
}

// all 4 weight-fold GEMMs in one dispatch (86 blocks)
__global__ __launch_bounds__(256) void fold_all(
    const f16* __restrict__ BtA,  const f16* __restrict__ uW2h,
    const f16* __restrict__ mW2h, const f16* __restrict__ uW1aT,
    const f16* __restrict__ uW1bT,const f16* __restrict__ oWTh,
    f16* __restrict__ BtPQ, f16* __restrict__ BtU, f16* __restrict__ Wp2t)
{
  __shared__ f16 As[128*64];
  __shared__ f16 Bs[128*64];
  const int b = blockIdx.x;
  if (b < 40) {
    int z = b >> 3, rem = b & 7, x = rem & 3, y = rem >> 2;
    gemm_core256(BtA + (size_t)(z+1)*131072, 256, uW2h + (size_t)z*65536, 256,
                 BtPQ + (size_t)(z+1)*131072, 256, x*128, y*128, As, Bs);
  } else if (b < 60) {
    int rem = b - 40, z = rem >> 2, r2 = rem & 3, x = r2 & 1, y = r2 >> 1;
    gemm_core256(uW1aT + (size_t)(z+1)*65536, 256, uW2h + (size_t)z*65536, 256,
                 BtU + (size_t)(z+1)*131072, 512, x*128, y*128, As, Bs);
  } else if (b < 84) {
    int rem = b - 60, z = rem >> 2, r2 = rem & 3, x = r2 & 1, y = r2 >> 1;
    gemm_core256(uW1bT + (size_t)z*65536, 256, mW2h + (size_t)z*65536, 256,
                 BtU + (size_t)z*131072 + 256, 512, x*128, y*128, As, Bs);
  } else {
    int y = b - 84;
    gemm_core256(oWTh, 256, uW2h + (size_t)5*65536, 256,
                 Wp2t, 256, 0, y*128, As, Bs);
  }
}

// R[n] = sum over valid dirs of relu(P[src]+Q[n]+cvec_d+(si/256)*wsi+(sj/256)*wsj)
template<int R1>
__global__ __launch_bounds__(256) void edge_fuse(
    const f16* __restrict__ PQ, f16* __restrict__ UR,
    const float* __restrict__ cvec, const float* __restrict__ wsi_,
    const float* __restrict__ wsj_,
    const int* __restrict__ gridv, const float* __restrict__ pa,
    const float* __restrict__ pc)
{
  const int t  = threadIdx.x;
  const int ln = t >> 5, ch = t & 31;
  int bid = blockIdx.x;
  bid = (bid & 7) * 1024 + (bid >> 3);
  const int n  = bid*8 + ln;
  const int i  = n >> 8, j = n & 255;
  const int co = ch*8;

  float q[8], pa0[8], pc0[8];
  if (R1) {
    float g = (float)gridv[n];
#pragma unroll
    for (int e=0;e<8;e++) {
      pa0[e] = pa[co+e]; pc0[e] = pc[co+e];
      q[e] = g*pa[256+co+e] + pc[256+co+e];
    }
  } else {
    f16x8 qv = *(const f16x8*)&PQ[(size_t)n*512 + 256 + co];
#pragma unroll
    for (int e=0;e<8;e++) q[e] = (float)qv[e];
  }
  float wi[8], wj[8];
#pragma unroll
  for (int e=0;e<8;e++){ wi[e]=wsi_[co+e]; wj[e]=wsj_[co+e]; }
  float acc[8];
#pragma unroll
  for (int e=0;e<8;e++) acc[e]=0.f;

  const int DI[4] = {-1,1,0,0};
  const int DJ[4] = {0,0,-1,1};
#pragma unroll
  for (int d=0; d<4; ++d) {
    int si = i - DI[d], sj = j - DJ[d];
    if (si>=0 && si<HG && sj>=0 && sj<WGD) {
      int s = si*WGD + sj;
      float fsi = si * (1.f/HG), fsj = sj * (1.f/WGD);
      float pvf[8];
      if (R1) {
        float gs = (float)gridv[s];
#pragma unroll
        for (int e=0;e<8;e++) pvf[e] = gs*pa0[e] + pc0[e];
      } else {
        f16x8 pv = *(const f16x8*)&PQ[(size_t)s*512 + co];
#pragma unroll
        for (int e=0;e<8;e++) pvf[e] = (float)pv[e];
      }
#pragma unroll
      for (int e=0;e<8;e++) {
        float v = pvf[e] + q[e] + cvec[d*256+co+e] + fsi*wi[e] + fsj*wj[e];
        acc[e] += fmaxf(v, 0.f);
      }
    }
  }
  f16x8 outv;
#pragma unroll
  for (int e=0;e<8;e++) outv[e] = (f16)acc[e];
  *(f16x8*)&UR[(size_t)n*512 + 256 + co] = outv;
}

// out[n,0..9] = U6[n,:] @ Wp2t^T + ob2  via MFMA, 1 wave = 16 nodes
__global__ __launch_bounds__(256) void out_mfma(
    const f16* __restrict__ U,        // lda 512
    const f16* __restrict__ Wp2t,     // [128][256], rows >=10 zero
    const float* __restrict__ ob2,
    float* __restrict__ out)
{
  int lane = threadIdx.x & 63;
  int wv   = threadIdx.x >> 6;
  int nbase = blockIdx.x*64 + wv*16;
  f32x4 acc = (f32x4){0.f,0.f,0.f,0.f};
  int r  = lane & 15;
  int kg = (lane >> 4) * 8;
  const f16* Up = U + (size_t)(nbase + r)*512 + kg;
  const f16* Bp = Wp2t + r*256 + kg;
#pragma unroll
  for (int kt=0; kt<8; ++kt) {
    f16x8 af = *(const f16x8*)(Up + kt*32);
    f16x8 bf = *(const f16x8*)(Bp + kt*32);
    acc = __builtin_amdgcn_mfma_f32_16x16x32_f16(af, bf, acc, 0,0,0);
  }
  int col = lane & 15;
  int row0 = (lane>>4)*4;
  if (col < 10) {
    float bo = ob2[col];
#pragma unroll
    for (int rr=0; rr<4; ++rr)
      out[(size_t)(nbase + row0 + rr)*10 + col] = acc[rr] + bo;
  }
}

// ---- prep: everything small + all transpose-casts in ONE dispatch ----
__global__ __launch_bounds__(256) void prep_small(
    const float* __restrict__ uW2, const float* __restrict__ mW2,
    const float* __restrict__ oW,  const float* __restrict__ mW1,
    const float* __restrict__ mb1, const float* __restrict__ mb2,
    const float* __restrict__ uW1, const float* __restrict__ ub1,
    const float* __restrict__ ub2, const float* __restrict__ nb,
    const float* __restrict__ nW,  const float* __restrict__ ob,
    f16* __restrict__ uW2h, f16* __restrict__ mW2h, f16* __restrict__ oWTh,
    float* __restrict__ cvec, float* __restrict__ wsi_, float* __restrict__ wsj_,
    float* __restrict__ v2, float* __restrict__ ubias, float* __restrict__ avec,
    float* __restrict__ pqb, float* __restrict__ pa, float* __restrict__ pc,
    float* __restrict__ ob2,
    f16* __restrict__ BtA, f16* __restrict__ uW1aT, f16* __restrict__ uW1bT)
{
  __shared__ float red[3][4][64];
  __shared__ float tbuf[32][33];
  const int b = blockIdx.x;
  const int tid = threadIdx.x;
  if (b < 1536) {
    int idx = b*256 + tid;
    uW2h[idx] = (f16)uW2[idx];
    mW2h[idx] = (f16)mW2[idx];
  } else if (b < 1664) {
    int c = b - 1536, j = tid;
    oWTh[c*256 + j] = (c < 10) ? (f16)oW[j*10 + c] : (f16)0.f;
  } else if (b < 1670) {
    int l = b - 1664, j = tid;
    const float* base = mW1 + (size_t)l*516*256;
    float w512 = base[512*256 + j], w513 = base[513*256 + j];
    float b1 = mb1[l*256 + j];
    const int DI[4] = {-1,1,0,0};
    const int DJ[4] = {0,0,-1,1};
    for (int d=0;d<4;d++)
      cvec[(l*4+d)*256 + j] = (float)DI[d]*w512 + (float)DJ[d]*w513 + b1;
    wsi_[l*256+j] = base[514*256 + j];
    wsj_[l*256+j] = base[515*256 + j];
  } else if (b < 1694) {
    int pr = tid & 63, q = tid >> 6;
    int pair = (b-1670)*64 + pr;
    int l = pair >> 8, j = pair & 255;
    const float* prevb = l ? (ub2 + (l-1)*256) : nb;
    float s1=0.f, s2=0.f, s3=0.f;
    for (int t = q*64; t < q*64+64; ++t) {
      s1 += mb2[l*256+t] * uW1[((size_t)l*512+256+t)*256 + j];
      s2 += prevb[t]     * uW1[((size_t)l*512+t)*256 + j];
      if (l==0) s3 += nW[t] * uW1[(size_t)t*256 + j];
    }
    red[0][q][pr]=s1; red[1][q][pr]=s2; red[2][q][pr]=s3;
    __syncthreads();
    if (q==0) {
      float a = red[0][0][pr]+red[0][1][pr]+red[0][2][pr]+red[0][3][pr];
      float bb = red[1][0][pr]+red[1][1][pr]+red[1][2][pr]+red[1][3][pr];
      v2[pair] = a;
      ubias[pair] = ub1[pair] + bb;
      if (l==0) avec[j] = red[2][0][pr]+red[2][1][pr]+red[2][2][pr]+red[2][3][pr];
    }
  } else if (b < 1742) {
    int pr = tid & 63, q = tid >> 6;
    int pair = (b-1694)*64 + pr;
    int l = pair >> 9, c = pair & 511;
    int rowoff = (c < 256) ? 0 : 256;
    int cc = c & 255;
    const float* base = mW1 + (size_t)l*516*256 + (size_t)rowoff*256 + cc;
    float s1=0.f, s2=0.f;
    if (l==0) {
      for (int j=q*64; j<q*64+64; ++j) { float wv = base[(size_t)j*256]; s1 += nW[j]*wv; s2 += nb[j]*wv; }
    } else {
      const float* pb = ub2 + (l-1)*256;
      for (int j=q*64; j<q*64+64; ++j) s1 += pb[j]*base[(size_t)j*256];
    }
    red[0][q][pr]=s1; red[1][q][pr]=s2;
    __syncthreads();
    if (q==0) {
      float a = red[0][0][pr]+red[0][1][pr]+red[0][2][pr]+red[0][3][pr];
      if (l==0) { pa[c]=a; pc[c]=red[1][0][pr]+red[1][1][pr]+red[1][2][pr]+red[1][3][pr]; }
      else pqb[pair] = a;
    }
  } else if (b == 1742) {
    int c = tid >> 4, jg = tid & 15;
    float s = 0.f;
    if (c < 10)
      for (int j=jg*16; j<jg*16+16; ++j) s += ub2[5*256+j]*oW[j*10+c];
    red[0][c>>2][(c&3)*16+jg] = s;
    __syncthreads();
    if (jg==0 && c < 16) {
      float a=0.f;
      for (int t2=0;t2<16;t2++) a += red[0][c>>2][(c&3)*16+t2];
      ob2[c] = (c < 10) ? a + ob[c] : 0.f;
    }
  } else {
    int t = b - 1743;
    int z = t >> 6, rem = t & 63;
    int bxs = (rem & 7) * 32, bys = (rem >> 3) * 32;
    const int q = z / 6, l = z % 6;
    const float* s;
    f16* d;
    if (q == 0)      { s = mW1 + (size_t)l*516*256;          d = BtA   + (size_t)l*131072; }
    else if (q == 1) { s = mW1 + (size_t)l*516*256 + 65536;  d = BtA   + (size_t)l*131072 + 65536; }
    else if (q == 2) { s = uW1 + (size_t)l*131072;           d = uW1aT + (size_t)l*65536; }
    else             { s = uW1 + (size_t)l*131072 + 65536;   d = uW1bT + (size_t)l*65536; }
    const int tx = tid & 31, ty = tid >> 5;
#pragma unroll
    for (int rr=0; rr<4; ++rr)
      tbuf[ty+rr*8][tx] = s[(size_t)(bys+ty+rr*8)*256 + bxs+tx];
    __syncthreads();
#pragma unroll
    for (int rr=0; rr<4; ++rr)
      d[(size_t)(bxs+ty+rr*8)*256 + bys+tx] = (f16)tbuf[tx][ty+rr*8];
  }
}

extern "C" void kernel_launch(void* const* d_in, const int* in_sizes, int n_in,
                              void* d_out, int out_size, void* d_ws, size_t ws_size,
                              hipStream_t stream)
{
  const int*   gridv = (const int*) d_in[0];
  const float* nW   = (const float*)d_in[3];
  const float* nb   = (const float*)d_in[4];
  const float* mW1  = (const float*)d_in[5];
  const float* mb1  = (const float*)d_in[6];
  const float* mW2  = (const float*)d_in[7];
  const float* mb2  = (const float*)d_in[8];
  const float* uW1  = (const float*)d_in[9];
  const float* ub1  = (const float*)d_in[10];
  const float* uW2  = (const float*)d_in[11];
  const float* ub2  = (const float*)d_in[12];
  const float* oW   = (const float*)d_in[13];
  const float* ob   = (const float*)d_in[14];
  float* out = (float*)d_out;

  char* ws = (char*)d_ws;
  size_t off = 0;
  f16* URa  = (f16*)(ws + off); off += (size_t)NN*512*2;
  f16* URb  = (f16*)(ws + off); off += (size_t)NN*512*2;
  f16* PQ   = (f16*)(ws + off); off += (size_t)NN*512*2;
  f16* BtA  = (f16*)(ws + off); off += 6*512*256*2;
  f16* BtPQ = (f16*)(ws + off); off += 6*512*256*2;   // slot 0 unused
  f16* BtU  = (f16*)(ws + off); off += 6*256*512*2;
  f16* BUf  = (f16*)(ws + off); off += 6*131072*2;    // fragment-major BtU
  f16* BPQf = (f16*)(ws + off); off += 6*131072*2;    // fragment-major BtPQ
  f16* uW2h = (f16*)(ws + off); off += 6*256*256*2;
  f16* mW2h = (f16*)(ws + off); off += 6*256*256*2;
  f16* uW1aT= (f16*)(ws + off); off += 6*256*256*2;
  f16* uW1bT= (f16*)(ws + off); off += 6*256*256*2;
  f16* oWTh = (f16*)(ws + off); off += 128*256*2;
  f16* Wp2t = (f16*)(ws + off); off += 128*256*2;
  float* cvec = (float*)(ws + off); off += 6*4*256*4;
  float* wsi_ = (float*)(ws + off); off += 6*256*4;
  float* wsj_ = (float*)(ws + off); off += 6*256*4;
  float* v2   = (float*)(ws + off); off += 6*256*4;
  float* ubias= (float*)(ws + off); off += 6*256*4;
  float* pqb  = (float*)(ws + off); off += 6*512*4;   // slot 0 unused
  float* pa   = (float*)(ws + off); off += 512*4;
  float* pc   = (float*)(ws + off); off += 512*4;
  float* avec = (float*)(ws + off); off += 256*4;
  float* ob2  = (float*)(ws + off); off += 16*4;

  // ---- prep (3 dispatches) ----
  prep_small<<<3279,256,0,stream>>>(uW2, mW2, oW, mW1, mb1, mb2, uW1, ub1, ub2,
                                    nb, nW, ob,
                                    uW2h, mW2h, oWTh, cvec, wsi_, wsj_,
                                    v2, ubias, avec, pqb, pa, pc, ob2,
                                    BtA, uW1aT, uW1bT);
  fold_all<<<86,256,0,stream>>>(BtA, uW2h, mW2h, uW1aT, uW1bT, oWTh,
                                BtPQ, BtU, Wp2t);
  repack_frag<<<dim3(64,6,2),256,0,stream>>>(BtU, BtPQ, BUf, BPQf);

  // ---- layer 1: R_1 analytic, then merged U_1 + PQ_2 ----
  edge_fuse<1><<<8192,256,0,stream>>>(nullptr, URa, cvec, wsi_, wsj_, gridv, pa, pc);
  gemm_merge<256,3,1><<<1024,512,0,stream>>>(
      URa + 256, 512, BUf, BPQf + (size_t)1*131072,
      URb, PQ, ubias, v2, avec, gridv, pqb + 1*512);

  // ---- layers 2..5: edge_fuse + merged(U_l + PQ_{l+1}) ----
  f16* cur = URb; f16* nxt = URa;
  for (int l=1;l<5;l++){
    edge_fuse<0><<<8192,256,0,stream>>>(PQ, cur, cvec + l*1024, wsi_ + l*256, wsj_ + l*256,
                                        nullptr, nullptr, nullptr);
    gemm_merge<512,1,1><<<1024,512,0,stream>>>(
        cur, 512, BUf + (size_t)l*131072, BPQf + (size_t)(l+1)*131072,
        nxt, PQ, ubias + l*256, v2 + l*256, nullptr, nullptr, pqb + (l+1)*512);
    f16* t = cur; cur = nxt; nxt = t;
  }

  // ---- layer 6: edge_fuse + merged update (no PQ phase) ----
  edge_fuse<0><<<8192,256,0,stream>>>(PQ, cur, cvec + 5*1024, wsi_ + 5*256, wsj_ + 5*256,
                                      nullptr, nullptr, nullptr);
  gemm_merge<512,1,0><<<1024,512,0,stream>>>(
      cur, 512, BUf + (size_t)5*131072, nullptr,
      nxt, nullptr, ubias + 5*256, v2 + 5*256, nullptr, nullptr, nullptr);

  // out = U6 @ Wp2t^T + ob2
  out_mfma<<<1024,256,0,stream>>>(nxt, Wp2t, ob2, out);
}